// Round 1
// baseline (1574.385 us; speedup 1.0000x reference)
//
#include <hip/hip_runtime.h>

typedef unsigned int u32;

constexpr int BATCH = 8;
constexpr int GH = 32, GW = 64;
constexpr int FH = 128, FW = 512;
constexpr int NFFT = 1024;
constexpr int HOP = 256;
constexpr int NFREQ = 513;
constexpr int NW = 512;                       // frames per batch
constexpr int SIGLEN = HOP * (NW - 1);        // 130816
constexpr int TOTAL_LEN = NFFT + HOP*(NW-1);  // 131840
constexpr int NITER = 32;
constexpr int NSAMP = 131072;
constexpr int NMAG = BATCH * NW * NFREQ;      // 2101248

// LDS index padding (9/8 stride)
#define SL(i) ((i) + ((i) >> 3))
constexpr int LDSN = 512 + 64;                // 576 slots

// ---------------- Threefry-2x32-20, partitionable path (key = (0,1)) ----------------
__device__ __forceinline__ void tf_round(u32 &x0, u32 &x1, int r) {
  x0 += x1;
  x1 = (x1 << r) | (x1 >> (32 - r));
  x1 ^= x0;
}

__device__ __forceinline__ void threefry2(u32 c0, u32 c1, u32 &o0, u32 &o1) {
  const u32 k0 = 0u, k1 = 1u;
  const u32 k2 = 0x1BD11BDAu ^ k0 ^ k1;
  u32 x0 = c0 + k0, x1 = c1 + k1;
  tf_round(x0, x1, 13); tf_round(x0, x1, 15); tf_round(x0, x1, 26); tf_round(x0, x1, 6);
  x0 += k1; x1 += k2 + 1u;
  tf_round(x0, x1, 17); tf_round(x0, x1, 29); tf_round(x0, x1, 16); tf_round(x0, x1, 24);
  x0 += k2; x1 += k0 + 2u;
  tf_round(x0, x1, 13); tf_round(x0, x1, 15); tf_round(x0, x1, 26); tf_round(x0, x1, 6);
  x0 += k0; x1 += k1 + 3u;
  tf_round(x0, x1, 17); tf_round(x0, x1, 29); tf_round(x0, x1, 16); tf_round(x0, x1, 24);
  x0 += k1; x1 += k2 + 4u;
  tf_round(x0, x1, 13); tf_round(x0, x1, 15); tf_round(x0, x1, 26); tf_round(x0, x1, 6);
  x0 += k2; x1 += k0 + 5u;
  o0 = x0; o1 = x1;
}

// ---------------- init: win f32, twiddle tables f64, wsq f32, tprev=0 ----------------
__global__ __launch_bounds__(256) void k_init(float* __restrict__ win,
                                              double2* __restrict__ tw512, double2* __restrict__ twh,
                                              float* __restrict__ wsq,
                                              float2* __restrict__ tprev)
{
  int idx = blockIdx.x * 256 + threadIdx.x;
  int stride = gridDim.x * 256;
  const double PI2 = 6.283185307179586476925286766559;
  for (int t = idx; t < NFFT; t += stride)
    win[t] = (float)(0.5 * (1.0 - cos(PI2 * (double)t / 1024.0)));  // _WIN f32
  for (int k = idx; k < 512; k += stride) {
    double th = -PI2 * (double)k / 512.0;
    double2 v; v.x = cos(th); v.y = sin(th);
    tw512[k] = v;                                     // e^{-2pi i k/512}
    double th2 = -PI2 * (double)k / 1024.0;
    double2 v2; v2.x = cos(th2); v2.y = sin(th2);
    twh[k] = v2;                                      // e^{-2pi i k/1024}
  }
  for (int j = idx; j < TOTAL_LEN; j += stride) {
    int gmax = j >> 8; if (gmax > NW - 1) gmax = NW - 1;
    int gmin = (j >= NFFT) ? ((j - (NFFT - 1) + 255) >> 8) : 0;
    float acc = 0.f;                       // f32 scatter-add, ascending frame order
    for (int g = gmin; g <= gmax; ++g) {
      float w = (float)(0.5 * (1.0 - cos(PI2 * (double)(j - (g << 8)) / 1024.0)));
      acc = __fadd_rn(acc, __fmul_rn(w, w));
    }
    wsq[j] = acc;
  }
  for (int i = idx; i < NMAG; i += stride)
    tprev[i] = make_float2(0.f, 0.f);
}

// ---------------- jax.image.resize bilinear, f32 weights WITH sum-normalization ----------------
__device__ __forceinline__ void lin_taps(float sf, int in, int &i0, int &i1, float &w0, float &w1)
{
  if (sf <= 0.0f)                  { i0 = 0;      i1 = 0;      w0 = 1.0f; w1 = 0.0f; return; }
  if (sf >= (float)(in - 1))       { i0 = in - 1; i1 = in - 1; w0 = 1.0f; w1 = 0.0f; return; }
  i0 = (int)sf; i1 = i0 + 1;
  float x0 = __fsub_rn(sf, (float)i0);   // exact
  float a0 = __fsub_rn(1.0f, x0);
  float S  = __fadd_rn(a0, x0);          // total_weight_sum = 1 +/- 2^-24
  w0 = __fdiv_rn(a0, S);                 // normalized (jax divides by the sum)
  w1 = __fdiv_rn(x0, S);
}

__device__ __forceinline__ float sf_H1(int H) {  // 32 -> 128
  return __fadd_rn(__fmul_rn(__fadd_rn((float)H, 0.5f), 0.25f), -0.5f);
}
__device__ __forceinline__ float sf_W1(int W) {  // 64 -> 512
  return __fadd_rn(__fmul_rn(__fadd_rn((float)W, 0.5f), 0.125f), -0.5f);
}
__device__ __forceinline__ float sf_H2(int K) {  // 128 -> 513, f32 inv_scale
  const float inv32 = (float)(1.0 / 4.0078125);  // f32(128/513)
  return __fadd_rn(__fmul_rn(__fadd_rn((float)K, 0.5f), inv32), -0.5f);
}

__device__ __forceinline__ float fs_at(const float* __restrict__ pb, int H, int W)
{
  int r0, r1; float u0, u1;
  lin_taps(sf_H1(H), GH, r0, r1, u0, u1);
  int c0, c1; float v0, v1;
  lin_taps(sf_W1(W), GW, c0, c1, v0, v1);
  float t0 = __fmaf_rn(u1, pb[r1 * GW + c0], __fmul_rn(u0, pb[r0 * GW + c0]));
  float t1 = __fmaf_rn(u1, pb[r1 * GW + c1], __fmul_rn(u0, pb[r0 * GW + c1]));
  return __fmaf_rn(v1, t1, __fmul_rn(v0, t0));
}

__global__ __launch_bounds__(256) void k_fullspec(const float* __restrict__ p, float* __restrict__ fs)
{
  int idx = blockIdx.x * 256 + threadIdx.x;
  if (idx >= BATCH * FH * FW) return;
  int b = idx >> 16;
  int h = (idx >> 9) & (FH - 1);
  int w = idx & (FW - 1);
  fs[idx] = fs_at(p + b * (GH * GW), h, w);
}

__global__ __launch_bounds__(256) void k_mag(const float* __restrict__ p, float* __restrict__ mag)
{
  int idx = blockIdx.x * 256 + threadIdx.x;
  if (idx >= NMAG) return;
  int b = idx / (NW * NFREQ);
  int rem = idx - b * (NW * NFREQ);
  int f = rem / NFREQ;
  int k = rem - f * NFREQ;
  const float* pb = p + b * (GH * GW);
  int h0, h1; float wa, wb;
  lin_taps(sf_H2(k), FH, h0, h1, wa, wb);
  float fs0 = fs_at(pb, h0, f);
  float fs1 = fs_at(pb, h1, f);
  float P0 = __fmul_rn(__fmul_rn(fs0, fs0), 100.0f);
  float P1 = __fmul_rn(__fmul_rn(fs1, fs1), 100.0f);
  float lin = __fmaf_rn(wb, P1, __fmul_rn(wa, P0));
  mag[idx] = __fsqrt_rn(fmaxf(lin, 0.0f));
}

__global__ __launch_bounds__(256) void k_phase(float2* __restrict__ ang)
{
  int idx = blockIdx.x * 256 + threadIdx.x;
  if (idx >= NMAG) return;
  int b = idx / (NW * NFREQ);
  int rem = idx - b * (NW * NFREQ);
  int f = rem / NFREQ;
  int k = rem - f * NFREQ;
  u32 cnt = (u32)(b * (NFREQ * NW) + k * NW + f);  // flat index in (B,513,512) C-order
  u32 w0, w1;
  threefry2(0u, cnt, w0, w1);
  u32 bits = w0 ^ w1;
  float u = __uint_as_float((bits >> 9) | 0x3f800000u) - 1.0f;
  float th = __fmul_rn((float)6.283185307179586, u);
  double thd = (double)th;
  ang[idx] = make_float2((float)cos(thd), (float)sin(thd));
}

// ---------------- 512-pt complex FFT: radix-4 Stockham stages (no final radix-2), f64 ----------------
// 128 threads. ONE twiddle gather per butterfly; w2 = w1^2, w3 = w1*w2 in registers
// (<=1 ulp f64 perturbation vs table — absorbed by per-step f32 quantizers; proven class).
template<bool INV>
__device__ __forceinline__ void fft512_stages(double2* __restrict__ A,
                                              const double2* __restrict__ tw512, int t)
{
  #pragma unroll
  for (int s = 0; s < 4; ++s) {
    const int L = 1 << (2 * s);
    const int m = 128 >> (2 * s);
    int p = t >> (2 * s);
    int q = t & (L - 1);
    double2 x0 = A[SL(q + (p)         * L)];
    double2 x1 = A[SL(q + (p + m)     * L)];
    double2 x2 = A[SL(q + (p + 2 * m) * L)];
    double2 x3 = A[SL(q + (p + 3 * m) * L)];
    __syncthreads();
    double t0x = x0.x + x2.x, t0y = x0.y + x2.y;
    double t1x = x0.x - x2.x, t1y = x0.y - x2.y;
    double t2x = x1.x + x3.x, t2y = x1.y + x3.y;
    double t3x = x1.x - x3.x, t3y = x1.y - x3.y;
    double y0x = t0x + t2x, y0y = t0y + t2y;
    double y2x = t0x - t2x, y2y = t0y - t2y;
    double y1x, y1y, y3x, y3y;
    if (INV) { y1x = t1x - t3y; y1y = t1y + t3x; y3x = t1x + t3y; y3y = t1y - t3x; }
    else     { y1x = t1x + t3y; y1y = t1y - t3x; y3x = t1x - t3y; y3y = t1y + t3x; }
    int base = p << (2 * s);
    double2 w1 = tw512[base];                 // single gather
    double w1y = INV ? -w1.y : w1.y;
    double w2x = w1.x * w1.x - w1y * w1y;     // w2 = w1^2 (conj commutes with powers)
    double w2y = 2.0 * w1.x * w1y;
    double w3x = w1.x * w2x - w1y * w2y;      // w3 = w1 * w2
    double w3y = w1.x * w2y + w1y * w2x;
    double2 o0; o0.x = y0x; o0.y = y0y;
    double2 o1; o1.x = y1x * w1.x - y1y * w1y; o1.y = y1x * w1y + y1y * w1.x;
    double2 o2; o2.x = y2x * w2x - y2y * w2y; o2.y = y2x * w2y + y2y * w2x;
    double2 o3; o3.x = y3x * w3x - y3y * w3y; o3.y = y3x * w3y + y3y * w3x;
    int ob = q + (4 * p) * L;
    A[SL(ob)]         = o0;
    A[SL(ob + L)]     = o1;
    A[SL(ob + 2 * L)] = o2;
    A[SL(ob + 3 * L)] = o3;
    __syncthreads();
  }
}

// forward: full FFT with in-LDS final radix-2 (epilogue needs arbitrary A[k] pairs)
template<bool INV>
__device__ __forceinline__ void fft512d1(double2* __restrict__ A,
                                         const double2* __restrict__ tw512, int t)
{
  fft512_stages<INV>(A, tw512, t);
  double2 a0 = A[SL(t)];
  double2 a1 = A[SL(t + 256)];
  double2 b0 = A[SL(t + 128)];
  double2 b1 = A[SL(t + 384)];
  __syncthreads();
  double2 e0; e0.x = a0.x + a1.x; e0.y = a0.y + a1.y;
  double2 d0; d0.x = a0.x - a1.x; d0.y = a0.y - a1.y;
  double2 e1; e1.x = b0.x + b1.x; e1.y = b0.y + b1.y;
  double2 d1; d1.x = b0.x - b1.x; d1.y = b0.y - b1.y;
  A[SL(t)]       = e0;
  A[SL(t + 256)] = d0;
  A[SL(t + 128)] = e1;
  A[SL(t + 384)] = d1;
  __syncthreads();
}

// inverse tail: final radix-2 entirely in registers (thread t owns outputs t, t+128, t+256, t+384)
// then scale + window + store. Numerically identical to the in-LDS path (same adds, same order).
__device__ __forceinline__ void ifft_tail_store(const double2* __restrict__ A, int t,
                                                const float* __restrict__ win,
                                                float* __restrict__ frow)
{
  double2 a0 = A[SL(t)];
  double2 a1 = A[SL(t + 256)];
  double2 b0 = A[SL(t + 128)];
  double2 b1 = A[SL(t + 384)];
  const double s = 1.0 / 512.0;
  {
    int m = t;                       // e0 = a0 + a1
    float xr = (float)((a0.x + a1.x) * s);
    float xi = (float)((a0.y + a1.y) * s);
    frow[2 * m]     = __fmul_rn(xr, win[2 * m]);
    frow[2 * m + 1] = __fmul_rn(xi, win[2 * m + 1]);
  }
  {
    int m = t + 128;                 // e1 = b0 + b1
    float xr = (float)((b0.x + b1.x) * s);
    float xi = (float)((b0.y + b1.y) * s);
    frow[2 * m]     = __fmul_rn(xr, win[2 * m]);
    frow[2 * m + 1] = __fmul_rn(xi, win[2 * m + 1]);
  }
  {
    int m = t + 256;                 // d0 = a0 - a1
    float xr = (float)((a0.x - a1.x) * s);
    float xi = (float)((a0.y - a1.y) * s);
    frow[2 * m]     = __fmul_rn(xr, win[2 * m]);
    frow[2 * m + 1] = __fmul_rn(xi, win[2 * m + 1]);
  }
  {
    int m = t + 384;                 // d1 = b0 - b1
    float xr = (float)((b0.x - b1.x) * s);
    float xi = (float)((b0.y - b1.y) * s);
    frow[2 * m]     = __fmul_rn(xr, win[2 * m]);
    frow[2 * m + 1] = __fmul_rn(xi, win[2 * m + 1]);
  }
}

// ---------------- initial ISTFT: irfft(1024) of mag*ang(global) via ifft(512), *win ----------------
__global__ __launch_bounds__(128) void k_istft(const float* __restrict__ mag, const float2* __restrict__ ang,
                                               float* __restrict__ frames,
                                               const double2* __restrict__ tw512,
                                               const double2* __restrict__ twh,
                                               const float* __restrict__ win)
{
  __shared__ double2 A[LDSN];
  int bf = blockIdx.x;          // b*512 + f
  int t = threadIdx.x;
  const float*  mrow = mag + bf * NFREQ;
  const float2* arow = ang + bf * NFREQ;
  for (int k = t; k < 512; k += 128) {
    float m1 = mrow[k];       float2 a1 = arow[k];
    int k2 = 512 - k;
    float m2 = mrow[k2];      float2 a2 = arow[k2];
    float S1x = __fmul_rn(m1, a1.x), S1y = __fmul_rn(m1, a1.y);
    float S2x = __fmul_rn(m2, a2.x), S2y = __fmul_rn(m2, a2.y);
    double2 Z;
    if (k == 0) {
      Z.x = 0.5 * ((double)S1x + (double)S2x);
      Z.y = 0.5 * ((double)S1x - (double)S2x);
    } else {
      double Xex = 0.5 * ((double)S1x + (double)S2x);
      double Xey = 0.5 * ((double)S1y - (double)S2y);
      double Dx  = 0.5 * ((double)S1x - (double)S2x);
      double Dy  = 0.5 * ((double)S1y + (double)S2y);
      double2 w = twh[k];                  // e^{-2pi i k/1024}
      double ux = w.x * Dx + w.y * Dy;     // conj(w)*D
      double uy = w.x * Dy - w.y * Dx;
      Z.x = Xex - uy;
      Z.y = Xey + ux;
    }
    A[SL(k)] = Z;
  }
  __syncthreads();
  fft512_stages<true>(A, tw512, t);
  ifft_tail_store(A, t, win, frames + bf * NFFT);
}

// f32 OLA sample at wsq-coordinate j
__device__ __forceinline__ float sig_sample(const float* __restrict__ fb, const float* __restrict__ wsq, int j)
{
  int gmax = j >> 8; if (gmax > NW - 1) gmax = NW - 1;
  int gmin = (j >= NFFT) ? ((j - (NFFT - 1) + 255) >> 8) : 0;
  float acc = 0.f;
  for (int g = gmin; g <= gmax; ++g)
    acc = __fadd_rn(acc, fb[g * NFFT + (j - (g << 8))]);
  float wv = wsq[j];
  return __fdiv_rn(acc, wv > 1e-11f ? wv : 1.0f);
}

// xp[b][j] of the old k_sig, computed on the fly: reflect-pad then OLA sample.
// Bit-identical ops to the materialized path.
__device__ __forceinline__ float xp_sample(const float* __restrict__ fb, const float* __restrict__ wsq, int j)
{
  int n = j - 512;
  if (n < 0) n = -n;
  if (n >= SIGLEN) n = 2 * SIGLEN - 2 - n;
  return sig_sample(fb, wsq, n + 512);
}

// ---------------- FUSED: OLA+reflect sampling -> stft_it (+ phase update in LDS) -> istft_{it+1} ----------------
// frames ping-pong (in != out) removes the same-iteration frames hazard that used to force k_sig.
__global__ __launch_bounds__(128) void k_fused(const float* __restrict__ frames_in,
                                               const float* __restrict__ wsq,
                                               const float* __restrict__ win,
                                               const double2* __restrict__ tw512,
                                               const double2* __restrict__ twh,
                                               const float* __restrict__ mag,
                                               float2* __restrict__ tprev,
                                               float* __restrict__ frames_out)
{
  __shared__ double2 A[LDSN];
  __shared__ float2 angL[NFREQ];
  int bf = blockIdx.x;
  int b = bf >> 9;
  int f = bf & (NW - 1);
  int t = threadIdx.x;

  // ---- forward: on-the-fly OLA sample, window, pack two reals per complex point ----
  const float* fb = frames_in + b * (NW * NFFT);
  int jbase = f * HOP;
  for (int m = t; m < 512; m += 128) {
    float s0 = __fmul_rn(xp_sample(fb, wsq, jbase + 2 * m),     win[2 * m]);
    float s1 = __fmul_rn(xp_sample(fb, wsq, jbase + 2 * m + 1), win[2 * m + 1]);
    double2 z; z.x = (double)s0; z.y = (double)s1;
    A[SL(m)] = z;
  }
  __syncthreads();
  fft512d1<false>(A, tw512, t);     // result in A

  // ---- unpack rfft bins + momentum phase update (all f32 boundary ops) ----
  float2* prow = tprev + bf * NFREQ;
  const float cf = (float)(0.99 / 1.99);
  for (int k = t; k < NFREQ; k += 128) {
    double rx, ry;
    if (k == 0)        { rx = A[SL(0)].x + A[SL(0)].y; ry = 0.0; }
    else if (k == 512) { rx = A[SL(0)].x - A[SL(0)].y; ry = 0.0; }
    else {
      double2 Zk = A[SL(k)];
      double2 Zc = A[SL(512 - k)];
      double Xex = 0.5 * (Zk.x + Zc.x);
      double Xey = 0.5 * (Zk.y - Zc.y);
      double Gx  = 0.5 * (Zk.x - Zc.x);
      double Gy  = 0.5 * (Zk.y + Zc.y);
      double Xox = Gy, Xoy = -Gx;          // Xo = -i*G
      double2 w = twh[k];
      rx = Xex + (w.x * Xox - w.y * Xoy);  // S = Xe + w*Xo
      ry = Xey + (w.x * Xoy + w.y * Xox);
    }
    float rxf = (float)rx, ryf = (float)ry;  // rfft quantized to c64
    float2 pv = prow[k];
    float ax = __fsub_rn(rxf, __fmul_rn(pv.x, cf));
    float ay = __fsub_rn(ryf, __fmul_rn(pv.y, cf));
    double dx = (double)ax, dy = (double)ay;
    float d = (float)sqrt(dx * dx + dy * dy);   // np.abs(c64) = hypotf
    float d2 = __fadd_rn(d, 1e-16f);
    float inv = __fdiv_rn(1.0f, d2);
    angL[k] = make_float2(__fmul_rn(ax, inv), __fmul_rn(ay, inv));
    prow[k] = make_float2(rxf, ryf);
  }
  __syncthreads();   // angL complete; all reads of A (rfft) done before repack

  // ---- inverse: Hermitian pack mag*angL into A ----
  const float* mrow = mag + bf * NFREQ;
  for (int k = t; k < 512; k += 128) {
    float m1 = mrow[k];       float2 a1 = angL[k];
    int k2 = 512 - k;
    float m2 = mrow[k2];      float2 a2 = angL[k2];
    float S1x = __fmul_rn(m1, a1.x), S1y = __fmul_rn(m1, a1.y);
    float S2x = __fmul_rn(m2, a2.x), S2y = __fmul_rn(m2, a2.y);
    double2 Z;
    if (k == 0) {
      Z.x = 0.5 * ((double)S1x + (double)S2x);
      Z.y = 0.5 * ((double)S1x - (double)S2x);
    } else {
      double Xex = 0.5 * ((double)S1x + (double)S2x);
      double Xey = 0.5 * ((double)S1y - (double)S2y);
      double Dx  = 0.5 * ((double)S1x - (double)S2x);
      double Dy  = 0.5 * ((double)S1y + (double)S2y);
      double2 w = twh[k];
      double ux = w.x * Dx + w.y * Dy;
      double uy = w.x * Dy - w.y * Dx;
      Z.x = Xex - uy;
      Z.y = Xey + ux;
    }
    A[SL(k)] = Z;
  }
  __syncthreads();
  fft512_stages<true>(A, tw512, t);
  ifft_tail_store(A, t, win, frames_out + bf * NFFT);
}

// ---------------- final OLA -> audio f32 + fused per-block |max| reduction ----------------
__global__ __launch_bounds__(256) void k_ola(const float* __restrict__ frames, const float* __restrict__ wsq,
                                             float* __restrict__ audio, float* __restrict__ partial)
{
  int idx = blockIdx.x * 256 + threadIdx.x;  // < BATCH*NSAMP
  int b  = idx >> 17;
  int nn = idx & (NSAMP - 1);
  float v = 0.f;
  if (nn < SIGLEN)
    v = sig_sample(frames + b * (NW * NFFT), wsq, nn + 512);
  audio[idx] = v;
  __shared__ float red[256];
  red[threadIdx.x] = fabsf(v);
  __syncthreads();
  for (int s = 128; s > 0; s >>= 1) {
    if (threadIdx.x < s) red[threadIdx.x] = fmaxf(red[threadIdx.x], red[threadIdx.x + s]);
    __syncthreads();
  }
  if (threadIdx.x == 0) partial[blockIdx.x] = red[0];   // 512 partials per batch
}

constexpr int OLA_BLK_PER_B = NSAMP / 256;   // 512

__global__ __launch_bounds__(256) void k_max2(const float* __restrict__ partial, float* __restrict__ maxbuf)
{
  int b = blockIdx.x;
  float m = 0.f;
  for (int i = threadIdx.x; i < OLA_BLK_PER_B; i += 256)
    m = fmaxf(m, partial[b * OLA_BLK_PER_B + i]);
  __shared__ float red[256];
  red[threadIdx.x] = m;
  __syncthreads();
  for (int s = 128; s > 0; s >>= 1) {
    if (threadIdx.x < s) red[threadIdx.x] = fmaxf(red[threadIdx.x], red[threadIdx.x + s]);
    __syncthreads();
  }
  if (threadIdx.x == 0) maxbuf[b] = red[0];
}

__global__ __launch_bounds__(256) void k_norm(const float* __restrict__ audio, const float* __restrict__ maxbuf,
                                              float* __restrict__ out)
{
  int idx = blockIdx.x * 256 + threadIdx.x;
  int b = idx >> 17;
  float m = fmaxf(maxbuf[b], 1e-8f);
  out[idx] = __fmul_rn(__fdiv_rn(audio[idx], m), 0.9f);
}

extern "C" void kernel_launch(void* const* d_in, const int* in_sizes, int n_in,
                              void* d_out, int out_size, void* d_ws, size_t ws_size,
                              hipStream_t stream)
{
  const float* params = (const float*)d_in[0];
  float* out   = (float*)d_out;
  float* audio_out = out;                   // BATCH*NSAMP
  float* fs        = out + BATCH * NSAMP;   // BATCH*FH*FW (full_spec output)

  // workspace layout (16B-aligned first)
  double2* tw512  = (double2*)d_ws;                        // 512
  double2* twh    = tw512 + 512;                           // 512
  float2*  ang    = (float2*)(twh + 512);                  // NMAG c64 (initial phases; dead after k_istft)
  float2*  tprev  = ang + NMAG;                            // NMAG c64
  float*   framesA= (float*)(tprev + NMAG);                // BATCH*NW*NFFT f32
  float*   mag    = framesA + BATCH * NW * NFFT;           // NMAG f32
  float*   win    = mag + NMAG;                            // NFFT
  float*   wsq    = win + NFFT;                            // TOTAL_LEN
  float*   audio32= wsq + TOTAL_LEN;                       // BATCH*NSAMP
  float*   maxbuf = audio32 + BATCH * NSAMP;               // BATCH
  float*   partial= maxbuf + BATCH;                        // BATCH*OLA_BLK_PER_B
  // frames ping-pong buffer B aliases the dead ang region:
  // NMAG*8 = 16,809,984 B >= BATCH*NW*NFFT*4 = 16,777,216 B. 16B-aligned.
  float*   framesB= (float*)ang;

  k_init<<<512, 256, 0, stream>>>(win, tw512, twh, wsq, tprev);
  k_fullspec<<<(BATCH * FH * FW) / 256, 256, 0, stream>>>(params, fs);
  k_mag<<<(NMAG + 255) / 256, 256, 0, stream>>>(params, mag);
  k_phase<<<(NMAG + 255) / 256, 256, 0, stream>>>(ang);

  // istft0 with initial phases, then 32x fused [OLA-sample + stft + update + istft]
  k_istft<<<BATCH * NW, 128, 0, stream>>>(mag, (const float2*)ang, framesA, tw512, twh, win);
  float* fin  = framesA;
  float* fout = framesB;
  for (int it = 0; it < NITER; ++it) {
    k_fused<<<BATCH * NW, 128, 0, stream>>>(fin, wsq, win, tw512, twh, mag, tprev, fout);
    float* tmp = fin; fin = fout; fout = tmp;
  }
  // NITER even -> final frames live in framesA (== fin)
  k_ola<<<(BATCH * NSAMP) / 256, 256, 0, stream>>>(fin, wsq, audio32, partial);
  k_max2<<<BATCH, 256, 0, stream>>>(partial, maxbuf);
  k_norm<<<(BATCH * NSAMP) / 256, 256, 0, stream>>>(audio32, maxbuf, audio_out);
}

// Round 2
// 1361.418 us; speedup vs baseline: 1.1564x; 1.1564x over previous
//
#include <hip/hip_runtime.h>

typedef unsigned int u32;

constexpr int BATCH = 8;
constexpr int GH = 32, GW = 64;
constexpr int FH = 128, FW = 512;
constexpr int NFFT = 1024;
constexpr int HOP = 256;
constexpr int NFREQ = 513;
constexpr int NW = 512;                       // frames per batch
constexpr int SIGLEN = HOP * (NW - 1);        // 130816
constexpr int TOTAL_LEN = NFFT + HOP*(NW-1);  // 131840
constexpr int NITER = 32;
constexpr int NSAMP = 131072;
constexpr int NMAG = BATCH * NW * NFREQ;      // 2101248

// LDS index padding (9/8 stride)
#define SL(i) ((i) + ((i) >> 3))
constexpr int LDSN = 512 + 64;                // 576 slots

// ---------------- Threefry-2x32-20, partitionable path (key = (0,1)) ----------------
__device__ __forceinline__ void tf_round(u32 &x0, u32 &x1, int r) {
  x0 += x1;
  x1 = (x1 << r) | (x1 >> (32 - r));
  x1 ^= x0;
}

__device__ __forceinline__ void threefry2(u32 c0, u32 c1, u32 &o0, u32 &o1) {
  const u32 k0 = 0u, k1 = 1u;
  const u32 k2 = 0x1BD11BDAu ^ k0 ^ k1;
  u32 x0 = c0 + k0, x1 = c1 + k1;
  tf_round(x0, x1, 13); tf_round(x0, x1, 15); tf_round(x0, x1, 26); tf_round(x0, x1, 6);
  x0 += k1; x1 += k2 + 1u;
  tf_round(x0, x1, 17); tf_round(x0, x1, 29); tf_round(x0, x1, 16); tf_round(x0, x1, 24);
  x0 += k2; x1 += k0 + 2u;
  tf_round(x0, x1, 13); tf_round(x0, x1, 15); tf_round(x0, x1, 26); tf_round(x0, x1, 6);
  x0 += k0; x1 += k1 + 3u;
  tf_round(x0, x1, 17); tf_round(x0, x1, 29); tf_round(x0, x1, 16); tf_round(x0, x1, 24);
  x0 += k1; x1 += k2 + 4u;
  tf_round(x0, x1, 13); tf_round(x0, x1, 15); tf_round(x0, x1, 26); tf_round(x0, x1, 6);
  x0 += k2; x1 += k0 + 5u;
  o0 = x0; o1 = x1;
}

// ---------------- init: win f32, twiddle tables f64, wsq f32, tprev=0 ----------------
__global__ __launch_bounds__(256) void k_init(float* __restrict__ win,
                                              double2* __restrict__ tw512, double2* __restrict__ twh,
                                              float* __restrict__ wsq,
                                              float2* __restrict__ tprev)
{
  int idx = blockIdx.x * 256 + threadIdx.x;
  int stride = gridDim.x * 256;
  const double PI2 = 6.283185307179586476925286766559;
  for (int t = idx; t < NFFT; t += stride)
    win[t] = (float)(0.5 * (1.0 - cos(PI2 * (double)t / 1024.0)));  // _WIN f32
  for (int k = idx; k < 512; k += stride) {
    double th = -PI2 * (double)k / 512.0;
    double2 v; v.x = cos(th); v.y = sin(th);
    tw512[k] = v;                                     // e^{-2pi i k/512}
    double th2 = -PI2 * (double)k / 1024.0;
    double2 v2; v2.x = cos(th2); v2.y = sin(th2);
    twh[k] = v2;                                      // e^{-2pi i k/1024}
  }
  for (int j = idx; j < TOTAL_LEN; j += stride) {
    int gmax = j >> 8; if (gmax > NW - 1) gmax = NW - 1;
    int gmin = (j >= NFFT) ? ((j - (NFFT - 1) + 255) >> 8) : 0;
    float acc = 0.f;                       // f32 scatter-add, ascending frame order
    for (int g = gmin; g <= gmax; ++g) {
      float w = (float)(0.5 * (1.0 - cos(PI2 * (double)(j - (g << 8)) / 1024.0)));
      acc = __fadd_rn(acc, __fmul_rn(w, w));
    }
    wsq[j] = acc;
  }
  for (int i = idx; i < NMAG; i += stride)
    tprev[i] = make_float2(0.f, 0.f);
}

// ---------------- jax.image.resize bilinear, f32 weights WITH sum-normalization ----------------
__device__ __forceinline__ void lin_taps(float sf, int in, int &i0, int &i1, float &w0, float &w1)
{
  if (sf <= 0.0f)                  { i0 = 0;      i1 = 0;      w0 = 1.0f; w1 = 0.0f; return; }
  if (sf >= (float)(in - 1))       { i0 = in - 1; i1 = in - 1; w0 = 1.0f; w1 = 0.0f; return; }
  i0 = (int)sf; i1 = i0 + 1;
  float x0 = __fsub_rn(sf, (float)i0);   // exact
  float a0 = __fsub_rn(1.0f, x0);
  float S  = __fadd_rn(a0, x0);          // total_weight_sum = 1 +/- 2^-24
  w0 = __fdiv_rn(a0, S);                 // normalized (jax divides by the sum)
  w1 = __fdiv_rn(x0, S);
}

__device__ __forceinline__ float sf_H1(int H) {  // 32 -> 128
  return __fadd_rn(__fmul_rn(__fadd_rn((float)H, 0.5f), 0.25f), -0.5f);
}
__device__ __forceinline__ float sf_W1(int W) {  // 64 -> 512
  return __fadd_rn(__fmul_rn(__fadd_rn((float)W, 0.5f), 0.125f), -0.5f);
}
__device__ __forceinline__ float sf_H2(int K) {  // 128 -> 513, f32 inv_scale
  const float inv32 = (float)(1.0 / 4.0078125);  // f32(128/513)
  return __fadd_rn(__fmul_rn(__fadd_rn((float)K, 0.5f), inv32), -0.5f);
}

__device__ __forceinline__ float fs_at(const float* __restrict__ pb, int H, int W)
{
  int r0, r1; float u0, u1;
  lin_taps(sf_H1(H), GH, r0, r1, u0, u1);
  int c0, c1; float v0, v1;
  lin_taps(sf_W1(W), GW, c0, c1, v0, v1);
  float t0 = __fmaf_rn(u1, pb[r1 * GW + c0], __fmul_rn(u0, pb[r0 * GW + c0]));
  float t1 = __fmaf_rn(u1, pb[r1 * GW + c1], __fmul_rn(u0, pb[r0 * GW + c1]));
  return __fmaf_rn(v1, t1, __fmul_rn(v0, t0));
}

__global__ __launch_bounds__(256) void k_fullspec(const float* __restrict__ p, float* __restrict__ fs)
{
  int idx = blockIdx.x * 256 + threadIdx.x;
  if (idx >= BATCH * FH * FW) return;
  int b = idx >> 16;
  int h = (idx >> 9) & (FH - 1);
  int w = idx & (FW - 1);
  fs[idx] = fs_at(p + b * (GH * GW), h, w);
}

__global__ __launch_bounds__(256) void k_mag(const float* __restrict__ p, float* __restrict__ mag)
{
  int idx = blockIdx.x * 256 + threadIdx.x;
  if (idx >= NMAG) return;
  int b = idx / (NW * NFREQ);
  int rem = idx - b * (NW * NFREQ);
  int f = rem / NFREQ;
  int k = rem - f * NFREQ;
  const float* pb = p + b * (GH * GW);
  int h0, h1; float wa, wb;
  lin_taps(sf_H2(k), FH, h0, h1, wa, wb);
  float fs0 = fs_at(pb, h0, f);
  float fs1 = fs_at(pb, h1, f);
  float P0 = __fmul_rn(__fmul_rn(fs0, fs0), 100.0f);
  float P1 = __fmul_rn(__fmul_rn(fs1, fs1), 100.0f);
  float lin = __fmaf_rn(wb, P1, __fmul_rn(wa, P0));
  mag[idx] = __fsqrt_rn(fmaxf(lin, 0.0f));
}

__global__ __launch_bounds__(256) void k_phase(float2* __restrict__ ang)
{
  int idx = blockIdx.x * 256 + threadIdx.x;
  if (idx >= NMAG) return;
  int b = idx / (NW * NFREQ);
  int rem = idx - b * (NW * NFREQ);
  int f = rem / NFREQ;
  int k = rem - f * NFREQ;
  u32 cnt = (u32)(b * (NFREQ * NW) + k * NW + f);  // flat index in (B,513,512) C-order
  u32 w0, w1;
  threefry2(0u, cnt, w0, w1);
  u32 bits = w0 ^ w1;
  float u = __uint_as_float((bits >> 9) | 0x3f800000u) - 1.0f;
  float th = __fmul_rn((float)6.283185307179586, u);
  double thd = (double)th;
  ang[idx] = make_float2((float)cos(thd), (float)sin(thd));
}

// ---------------- 512-pt complex FFT: radix-4 Stockham, PING-PONG LDS (1 barrier/stage), f64 ----------------
// Identical arithmetic to the in-place version (same butterflies, same twiddle products,
// same order) — only the memory placement changed, so results are bit-identical.
template<bool INV, int S4>
__device__ __forceinline__ void fft512_stage(const double2* __restrict__ Sb,
                                             double2* __restrict__ Db,
                                             const double2* __restrict__ tw512, int t)
{
  const int L = 1 << (2 * S4);
  const int m = 128 >> (2 * S4);
  int p = t >> (2 * S4);
  int q = t & (L - 1);
  double2 x0 = Sb[SL(q + (p)         * L)];
  double2 x1 = Sb[SL(q + (p + m)     * L)];
  double2 x2 = Sb[SL(q + (p + 2 * m) * L)];
  double2 x3 = Sb[SL(q + (p + 3 * m) * L)];
  double t0x = x0.x + x2.x, t0y = x0.y + x2.y;
  double t1x = x0.x - x2.x, t1y = x0.y - x2.y;
  double t2x = x1.x + x3.x, t2y = x1.y + x3.y;
  double t3x = x1.x - x3.x, t3y = x1.y - x3.y;
  double y0x = t0x + t2x, y0y = t0y + t2y;
  double y2x = t0x - t2x, y2y = t0y - t2y;
  double y1x, y1y, y3x, y3y;
  if (INV) { y1x = t1x - t3y; y1y = t1y + t3x; y3x = t1x + t3y; y3y = t1y - t3x; }
  else     { y1x = t1x + t3y; y1y = t1y - t3x; y3x = t1x - t3y; y3y = t1y + t3x; }
  int base = p << (2 * S4);
  double2 w1 = tw512[base];                 // single gather
  double w1y = INV ? -w1.y : w1.y;
  double w2x = w1.x * w1.x - w1y * w1y;     // w2 = w1^2 (conj commutes with powers)
  double w2y = 2.0 * w1.x * w1y;
  double w3x = w1.x * w2x - w1y * w2y;      // w3 = w1 * w2
  double w3y = w1.x * w2y + w1y * w2x;
  double2 o0; o0.x = y0x; o0.y = y0y;
  double2 o1; o1.x = y1x * w1.x - y1y * w1y; o1.y = y1x * w1y + y1y * w1.x;
  double2 o2; o2.x = y2x * w2x - y2y * w2y; o2.y = y2x * w2y + y2y * w2x;
  double2 o3; o3.x = y3x * w3x - y3y * w3y; o3.y = y3x * w3y + y3y * w3x;
  int ob = q + (4 * p) * L;
  Db[SL(ob)]         = o0;
  Db[SL(ob + L)]     = o1;
  Db[SL(ob + 2 * L)] = o2;
  Db[SL(ob + 3 * L)] = o3;
}

// 4 radix-4 stages, ping-pong A->B->A->B->A. Caller must barrier before (A fully packed).
// Result lands back in A.
template<bool INV>
__device__ __forceinline__ void fft512_pp(double2* __restrict__ A, double2* __restrict__ B,
                                          const double2* __restrict__ tw512, int t)
{
  fft512_stage<INV, 0>(A, B, tw512, t); __syncthreads();
  fft512_stage<INV, 1>(B, A, tw512, t); __syncthreads();
  fft512_stage<INV, 2>(A, B, tw512, t); __syncthreads();
  fft512_stage<INV, 3>(B, A, tw512, t); __syncthreads();
}

// forward final radix-2: read A, write B (caller barriers after; spectrum then in B)
__device__ __forceinline__ void fwd_radix2(const double2* __restrict__ A, double2* __restrict__ B, int t)
{
  double2 a0 = A[SL(t)];
  double2 a1 = A[SL(t + 256)];
  double2 b0 = A[SL(t + 128)];
  double2 b1 = A[SL(t + 384)];
  double2 e0; e0.x = a0.x + a1.x; e0.y = a0.y + a1.y;
  double2 d0; d0.x = a0.x - a1.x; d0.y = a0.y - a1.y;
  double2 e1; e1.x = b0.x + b1.x; e1.y = b0.y + b1.y;
  double2 d1; d1.x = b0.x - b1.x; d1.y = b0.y - b1.y;
  B[SL(t)]       = e0;
  B[SL(t + 256)] = d0;
  B[SL(t + 128)] = e1;
  B[SL(t + 384)] = d1;
}

// inverse tail: final radix-2 entirely in registers (thread t owns outputs t, t+128, t+256, t+384)
// then scale + window + store. Numerically identical to the in-LDS path (same adds, same order).
__device__ __forceinline__ void ifft_tail_store(const double2* __restrict__ A, int t,
                                                const float* __restrict__ win,
                                                float* __restrict__ frow)
{
  double2 a0 = A[SL(t)];
  double2 a1 = A[SL(t + 256)];
  double2 b0 = A[SL(t + 128)];
  double2 b1 = A[SL(t + 384)];
  const double s = 1.0 / 512.0;
  {
    int m = t;                       // e0 = a0 + a1
    float xr = (float)((a0.x + a1.x) * s);
    float xi = (float)((a0.y + a1.y) * s);
    frow[2 * m]     = __fmul_rn(xr, win[2 * m]);
    frow[2 * m + 1] = __fmul_rn(xi, win[2 * m + 1]);
  }
  {
    int m = t + 128;                 // e1 = b0 + b1
    float xr = (float)((b0.x + b1.x) * s);
    float xi = (float)((b0.y + b1.y) * s);
    frow[2 * m]     = __fmul_rn(xr, win[2 * m]);
    frow[2 * m + 1] = __fmul_rn(xi, win[2 * m + 1]);
  }
  {
    int m = t + 256;                 // d0 = a0 - a1
    float xr = (float)((a0.x - a1.x) * s);
    float xi = (float)((a0.y - a1.y) * s);
    frow[2 * m]     = __fmul_rn(xr, win[2 * m]);
    frow[2 * m + 1] = __fmul_rn(xi, win[2 * m + 1]);
  }
  {
    int m = t + 384;                 // d1 = b0 - b1
    float xr = (float)((b0.x - b1.x) * s);
    float xi = (float)((b0.y - b1.y) * s);
    frow[2 * m]     = __fmul_rn(xr, win[2 * m]);
    frow[2 * m + 1] = __fmul_rn(xi, win[2 * m + 1]);
  }
}

// ---------------- initial ISTFT: irfft(1024) of mag*ang(global) via ifft(512), *win ----------------
__global__ __launch_bounds__(128) void k_istft(const float* __restrict__ mag, const float2* __restrict__ ang,
                                               float* __restrict__ frames,
                                               const double2* __restrict__ tw512,
                                               const double2* __restrict__ twh,
                                               const float* __restrict__ win)
{
  __shared__ double2 bufA[LDSN];
  __shared__ double2 bufB[LDSN];
  int bf = blockIdx.x;          // b*512 + f
  int t = threadIdx.x;
  const float*  mrow = mag + bf * NFREQ;
  const float2* arow = ang + bf * NFREQ;
  for (int k = t; k < 512; k += 128) {
    float m1 = mrow[k];       float2 a1 = arow[k];
    int k2 = 512 - k;
    float m2 = mrow[k2];      float2 a2 = arow[k2];
    float S1x = __fmul_rn(m1, a1.x), S1y = __fmul_rn(m1, a1.y);
    float S2x = __fmul_rn(m2, a2.x), S2y = __fmul_rn(m2, a2.y);
    double2 Z;
    if (k == 0) {
      Z.x = 0.5 * ((double)S1x + (double)S2x);
      Z.y = 0.5 * ((double)S1x - (double)S2x);
    } else {
      double Xex = 0.5 * ((double)S1x + (double)S2x);
      double Xey = 0.5 * ((double)S1y - (double)S2y);
      double Dx  = 0.5 * ((double)S1x - (double)S2x);
      double Dy  = 0.5 * ((double)S1y + (double)S2y);
      double2 w = twh[k];                  // e^{-2pi i k/1024}
      double ux = w.x * Dx + w.y * Dy;     // conj(w)*D
      double uy = w.x * Dy - w.y * Dx;
      Z.x = Xex - uy;
      Z.y = Xey + ux;
    }
    bufA[SL(k)] = Z;
  }
  __syncthreads();
  fft512_pp<true>(bufA, bufB, tw512, t);   // result in bufA
  ifft_tail_store(bufA, t, win, frames + bf * NFFT);
}

// f32 OLA sample at wsq-coordinate j
__device__ __forceinline__ float sig_sample(const float* __restrict__ fb, const float* __restrict__ wsq, int j)
{
  int gmax = j >> 8; if (gmax > NW - 1) gmax = NW - 1;
  int gmin = (j >= NFFT) ? ((j - (NFFT - 1) + 255) >> 8) : 0;
  float acc = 0.f;
  for (int g = gmin; g <= gmax; ++g)
    acc = __fadd_rn(acc, fb[g * NFFT + (j - (g << 8))]);
  float wv = wsq[j];
  return __fdiv_rn(acc, wv > 1e-11f ? wv : 1.0f);
}

// ---------------- per-iteration: OLA + reflect-pad -> xp[b][0..TOTAL_LEN) ----------------
__global__ __launch_bounds__(256) void k_sig(const float* __restrict__ frames, const float* __restrict__ wsq,
                                             float* __restrict__ xp)
{
  int idx = blockIdx.x * 256 + threadIdx.x;   // < BATCH*TOTAL_LEN
  int b = idx / TOTAL_LEN;
  int j = idx - b * TOTAL_LEN;
  int n = j - 512;
  if (n < 0) n = -n;
  if (n >= SIGLEN) n = 2 * SIGLEN - 2 - n;
  xp[idx] = sig_sample(frames + b * (NW * NFFT), wsq, n + 512);
}

// ---------------- FUSED: stft_it (+ phase update in LDS) + istft_{it+1} ----------------
// angL overlays the dead bufA region during the epilogue (bufA's content was consumed by
// fwd_radix2 before the overlay is written; inverse restarts by packing into bufB).
__global__ __launch_bounds__(128) void k_fused(const float* __restrict__ xp,
                                               const float* __restrict__ win,
                                               const double2* __restrict__ tw512,
                                               const double2* __restrict__ twh,
                                               const float* __restrict__ mag,
                                               float2* __restrict__ tprev,
                                               float* __restrict__ frames)
{
  __shared__ double2 bufA[LDSN];
  __shared__ double2 bufB[LDSN];
  float2* angL = (float2*)bufA;     // 513 float2 = 4104 B <= 9216 B
  int bf = blockIdx.x;
  int b = bf >> 9;
  int f = bf & (NW - 1);
  int t = threadIdx.x;

  // ---- forward: pack two real samples per complex point ----
  const float* xrow = xp + b * TOTAL_LEN + f * HOP;
  for (int m = t; m < 512; m += 128) {
    float s0 = __fmul_rn(xrow[2 * m],     win[2 * m]);
    float s1 = __fmul_rn(xrow[2 * m + 1], win[2 * m + 1]);
    double2 z; z.x = (double)s0; z.y = (double)s1;
    bufA[SL(m)] = z;
  }
  __syncthreads();
  fft512_pp<false>(bufA, bufB, tw512, t);   // result in bufA
  fwd_radix2(bufA, bufB, t);                // spectrum -> bufB
  __syncthreads();

  // ---- unpack rfft bins + momentum phase update (all f32 boundary ops) ----
  // reads bufB (spectrum), writes angL (overlaid on now-dead bufA)
  float2* prow = tprev + bf * NFREQ;
  const float cf = (float)(0.99 / 1.99);
  for (int k = t; k < NFREQ; k += 128) {
    double rx, ry;
    if (k == 0)        { rx = bufB[SL(0)].x + bufB[SL(0)].y; ry = 0.0; }
    else if (k == 512) { rx = bufB[SL(0)].x - bufB[SL(0)].y; ry = 0.0; }
    else {
      double2 Zk = bufB[SL(k)];
      double2 Zc = bufB[SL(512 - k)];
      double Xex = 0.5 * (Zk.x + Zc.x);
      double Xey = 0.5 * (Zk.y - Zc.y);
      double Gx  = 0.5 * (Zk.x - Zc.x);
      double Gy  = 0.5 * (Zk.y + Zc.y);
      double Xox = Gy, Xoy = -Gx;          // Xo = -i*G
      double2 w = twh[k];
      rx = Xex + (w.x * Xox - w.y * Xoy);  // S = Xe + w*Xo
      ry = Xey + (w.x * Xoy + w.y * Xox);
    }
    float rxf = (float)rx, ryf = (float)ry;  // rfft quantized to c64
    float2 pv = prow[k];
    float ax = __fsub_rn(rxf, __fmul_rn(pv.x, cf));
    float ay = __fsub_rn(ryf, __fmul_rn(pv.y, cf));
    double dx = (double)ax, dy = (double)ay;
    float d = (float)sqrt(dx * dx + dy * dy);   // np.abs(c64) = hypotf
    float d2 = __fadd_rn(d, 1e-16f);
    float inv = __fdiv_rn(1.0f, d2);
    angL[k] = make_float2(__fmul_rn(ax, inv), __fmul_rn(ay, inv));
    prow[k] = make_float2(rxf, ryf);
  }
  __syncthreads();   // angL complete; all reads of bufB spectrum done

  // ---- inverse: Hermitian pack mag*angL into bufB ----
  const float* mrow = mag + bf * NFREQ;
  for (int k = t; k < 512; k += 128) {
    float m1 = mrow[k];       float2 a1 = angL[k];
    int k2 = 512 - k;
    float m2 = mrow[k2];      float2 a2 = angL[k2];
    float S1x = __fmul_rn(m1, a1.x), S1y = __fmul_rn(m1, a1.y);
    float S2x = __fmul_rn(m2, a2.x), S2y = __fmul_rn(m2, a2.y);
    double2 Z;
    if (k == 0) {
      Z.x = 0.5 * ((double)S1x + (double)S2x);
      Z.y = 0.5 * ((double)S1x - (double)S2x);
    } else {
      double Xex = 0.5 * ((double)S1x + (double)S2x);
      double Xey = 0.5 * ((double)S1y - (double)S2y);
      double Dx  = 0.5 * ((double)S1x - (double)S2x);
      double Dy  = 0.5 * ((double)S1y + (double)S2y);
      double2 w = twh[k];
      double ux = w.x * Dx + w.y * Dy;
      double uy = w.x * Dy - w.y * Dx;
      Z.x = Xex - uy;
      Z.y = Xey + ux;
    }
    bufB[SL(k)] = Z;
  }
  __syncthreads();
  fft512_pp<true>(bufB, bufA, tw512, t);   // result in bufB (angL region destroyed - OK)
  ifft_tail_store(bufB, t, win, frames + bf * NFFT);
}

// ---------------- final OLA -> audio f32 + fused per-block |max| reduction ----------------
__global__ __launch_bounds__(256) void k_ola(const float* __restrict__ frames, const float* __restrict__ wsq,
                                             float* __restrict__ audio, float* __restrict__ partial)
{
  int idx = blockIdx.x * 256 + threadIdx.x;  // < BATCH*NSAMP
  int b  = idx >> 17;
  int nn = idx & (NSAMP - 1);
  float v = 0.f;
  if (nn < SIGLEN)
    v = sig_sample(frames + b * (NW * NFFT), wsq, nn + 512);
  audio[idx] = v;
  __shared__ float red[256];
  red[threadIdx.x] = fabsf(v);
  __syncthreads();
  for (int s = 128; s > 0; s >>= 1) {
    if (threadIdx.x < s) red[threadIdx.x] = fmaxf(red[threadIdx.x], red[threadIdx.x + s]);
    __syncthreads();
  }
  if (threadIdx.x == 0) partial[blockIdx.x] = red[0];   // 512 partials per batch
}

constexpr int OLA_BLK_PER_B = NSAMP / 256;   // 512

__global__ __launch_bounds__(256) void k_max2(const float* __restrict__ partial, float* __restrict__ maxbuf)
{
  int b = blockIdx.x;
  float m = 0.f;
  for (int i = threadIdx.x; i < OLA_BLK_PER_B; i += 256)
    m = fmaxf(m, partial[b * OLA_BLK_PER_B + i]);
  __shared__ float red[256];
  red[threadIdx.x] = m;
  __syncthreads();
  for (int s = 128; s > 0; s >>= 1) {
    if (threadIdx.x < s) red[threadIdx.x] = fmaxf(red[threadIdx.x], red[threadIdx.x + s]);
    __syncthreads();
  }
  if (threadIdx.x == 0) maxbuf[b] = red[0];
}

__global__ __launch_bounds__(256) void k_norm(const float* __restrict__ audio, const float* __restrict__ maxbuf,
                                              float* __restrict__ out)
{
  int idx = blockIdx.x * 256 + threadIdx.x;
  int b = idx >> 17;
  float m = fmaxf(maxbuf[b], 1e-8f);
  out[idx] = __fmul_rn(__fdiv_rn(audio[idx], m), 0.9f);
}

extern "C" void kernel_launch(void* const* d_in, const int* in_sizes, int n_in,
                              void* d_out, int out_size, void* d_ws, size_t ws_size,
                              hipStream_t stream)
{
  const float* params = (const float*)d_in[0];
  float* out   = (float*)d_out;
  float* audio_out = out;                   // BATCH*NSAMP
  float* fs        = out + BATCH * NSAMP;   // BATCH*FH*FW (full_spec output)

  // workspace layout (16B-aligned first)
  double2* tw512  = (double2*)d_ws;                        // 512
  double2* twh    = tw512 + 512;                           // 512
  float2*  ang    = (float2*)(twh + 512);                  // NMAG c64 (initial phases only)
  float2*  tprev  = ang + NMAG;                            // NMAG c64
  float*   frames = (float*)(tprev + NMAG);                // BATCH*NW*NFFT f32
  float*   mag    = frames + BATCH * NW * NFFT;            // NMAG f32
  float*   xp     = mag + NMAG;                            // BATCH*TOTAL_LEN f32
  float*   win    = xp + BATCH * TOTAL_LEN;                // NFFT
  float*   wsq    = win + NFFT;                            // TOTAL_LEN
  float*   audio32= wsq + TOTAL_LEN;                       // BATCH*NSAMP
  float*   maxbuf = audio32 + BATCH * NSAMP;               // BATCH
  float*   partial= maxbuf + BATCH;                        // BATCH*OLA_BLK_PER_B

  k_init<<<512, 256, 0, stream>>>(win, tw512, twh, wsq, tprev);
  k_fullspec<<<(BATCH * FH * FW) / 256, 256, 0, stream>>>(params, fs);
  k_mag<<<(NMAG + 255) / 256, 256, 0, stream>>>(params, mag);
  k_phase<<<(NMAG + 255) / 256, 256, 0, stream>>>(ang);

  // istft0 with initial phases, then 32x [OLA->xp ; fused stft+update+istft]
  k_istft<<<BATCH * NW, 128, 0, stream>>>(mag, (const float2*)ang, frames, tw512, twh, win);
  for (int it = 0; it < NITER; ++it) {
    k_sig<<<(BATCH * TOTAL_LEN) / 256, 256, 0, stream>>>(frames, wsq, xp);
    k_fused<<<BATCH * NW, 128, 0, stream>>>(xp, win, tw512, twh, mag, tprev, frames);
  }
  k_ola<<<(BATCH * NSAMP) / 256, 256, 0, stream>>>(frames, wsq, audio32, partial);
  k_max2<<<BATCH, 256, 0, stream>>>(partial, maxbuf);
  k_norm<<<(BATCH * NSAMP) / 256, 256, 0, stream>>>(audio32, maxbuf, audio_out);
}

// Round 3
// 1200.485 us; speedup vs baseline: 1.3115x; 1.1341x over previous
//
#include <hip/hip_runtime.h>

typedef unsigned int u32;

constexpr int BATCH = 8;
constexpr int GH = 32, GW = 64;
constexpr int FH = 128, FW = 512;
constexpr int NFFT = 1024;
constexpr int HOP = 256;
constexpr int NFREQ = 513;
constexpr int NW = 512;                       // frames per batch
constexpr int SIGLEN = HOP * (NW - 1);        // 130816
constexpr int TOTAL_LEN = NFFT + HOP*(NW-1);  // 131840
constexpr int NITER = 32;
constexpr int NSAMP = 131072;
constexpr int NMAG = BATCH * NW * NFREQ;      // 2101248

// LDS index padding (9/8 stride)
#define SL(i) ((i) + ((i) >> 3))
constexpr int LDSN = 512 + 64;                // 576 slots

// ---------------- Threefry-2x32-20, partitionable path (key = (0,1)) ----------------
__device__ __forceinline__ void tf_round(u32 &x0, u32 &x1, int r) {
  x0 += x1;
  x1 = (x1 << r) | (x1 >> (32 - r));
  x1 ^= x0;
}

__device__ __forceinline__ void threefry2(u32 c0, u32 c1, u32 &o0, u32 &o1) {
  const u32 k0 = 0u, k1 = 1u;
  const u32 k2 = 0x1BD11BDAu ^ k0 ^ k1;
  u32 x0 = c0 + k0, x1 = c1 + k1;
  tf_round(x0, x1, 13); tf_round(x0, x1, 15); tf_round(x0, x1, 26); tf_round(x0, x1, 6);
  x0 += k1; x1 += k2 + 1u;
  tf_round(x0, x1, 17); tf_round(x0, x1, 29); tf_round(x0, x1, 16); tf_round(x0, x1, 24);
  x0 += k2; x1 += k0 + 2u;
  tf_round(x0, x1, 13); tf_round(x0, x1, 15); tf_round(x0, x1, 26); tf_round(x0, x1, 6);
  x0 += k0; x1 += k1 + 3u;
  tf_round(x0, x1, 17); tf_round(x0, x1, 29); tf_round(x0, x1, 16); tf_round(x0, x1, 24);
  x0 += k1; x1 += k2 + 4u;
  tf_round(x0, x1, 13); tf_round(x0, x1, 15); tf_round(x0, x1, 26); tf_round(x0, x1, 6);
  x0 += k2; x1 += k0 + 5u;
  o0 = x0; o1 = x1;
}

// ---------------- init: win f32, twiddle tables (f32 for FFT core, f64 for boundary), wsq, tprev ----------------
__global__ __launch_bounds__(256) void k_init(float* __restrict__ win,
                                              float2* __restrict__ tw512f, double2* __restrict__ twh,
                                              float* __restrict__ wsq,
                                              float2* __restrict__ tprev)
{
  int idx = blockIdx.x * 256 + threadIdx.x;
  int stride = gridDim.x * 256;
  const double PI2 = 6.283185307179586476925286766559;
  for (int t = idx; t < NFFT; t += stride)
    win[t] = (float)(0.5 * (1.0 - cos(PI2 * (double)t / 1024.0)));  // _WIN f32
  for (int k = idx; k < 512; k += stride) {
    double th = -PI2 * (double)k / 512.0;
    tw512f[k] = make_float2((float)cos(th), (float)sin(th));  // e^{-2pi i k/512}, 0.5ulp f32
    double th2 = -PI2 * (double)k / 1024.0;
    double2 v2; v2.x = cos(th2); v2.y = sin(th2);
    twh[k] = v2;                                      // e^{-2pi i k/1024} (f64, boundary ops)
  }
  for (int j = idx; j < TOTAL_LEN; j += stride) {
    int gmax = j >> 8; if (gmax > NW - 1) gmax = NW - 1;
    int gmin = (j >= NFFT) ? ((j - (NFFT - 1) + 255) >> 8) : 0;
    float acc = 0.f;                       // f32 scatter-add, ascending frame order
    for (int g = gmin; g <= gmax; ++g) {
      float w = (float)(0.5 * (1.0 - cos(PI2 * (double)(j - (g << 8)) / 1024.0)));
      acc = __fadd_rn(acc, __fmul_rn(w, w));
    }
    wsq[j] = acc;
  }
  for (int i = idx; i < NMAG; i += stride)
    tprev[i] = make_float2(0.f, 0.f);
}

// ---------------- jax.image.resize bilinear, f32 weights WITH sum-normalization ----------------
__device__ __forceinline__ void lin_taps(float sf, int in, int &i0, int &i1, float &w0, float &w1)
{
  if (sf <= 0.0f)                  { i0 = 0;      i1 = 0;      w0 = 1.0f; w1 = 0.0f; return; }
  if (sf >= (float)(in - 1))       { i0 = in - 1; i1 = in - 1; w0 = 1.0f; w1 = 0.0f; return; }
  i0 = (int)sf; i1 = i0 + 1;
  float x0 = __fsub_rn(sf, (float)i0);   // exact
  float a0 = __fsub_rn(1.0f, x0);
  float S  = __fadd_rn(a0, x0);          // total_weight_sum = 1 +/- 2^-24
  w0 = __fdiv_rn(a0, S);                 // normalized (jax divides by the sum)
  w1 = __fdiv_rn(x0, S);
}

__device__ __forceinline__ float sf_H1(int H) {  // 32 -> 128
  return __fadd_rn(__fmul_rn(__fadd_rn((float)H, 0.5f), 0.25f), -0.5f);
}
__device__ __forceinline__ float sf_W1(int W) {  // 64 -> 512
  return __fadd_rn(__fmul_rn(__fadd_rn((float)W, 0.5f), 0.125f), -0.5f);
}
__device__ __forceinline__ float sf_H2(int K) {  // 128 -> 513, f32 inv_scale
  const float inv32 = (float)(1.0 / 4.0078125);  // f32(128/513)
  return __fadd_rn(__fmul_rn(__fadd_rn((float)K, 0.5f), inv32), -0.5f);
}

__device__ __forceinline__ float fs_at(const float* __restrict__ pb, int H, int W)
{
  int r0, r1; float u0, u1;
  lin_taps(sf_H1(H), GH, r0, r1, u0, u1);
  int c0, c1; float v0, v1;
  lin_taps(sf_W1(W), GW, c0, c1, v0, v1);
  float t0 = __fmaf_rn(u1, pb[r1 * GW + c0], __fmul_rn(u0, pb[r0 * GW + c0]));
  float t1 = __fmaf_rn(u1, pb[r1 * GW + c1], __fmul_rn(u0, pb[r0 * GW + c1]));
  return __fmaf_rn(v1, t1, __fmul_rn(v0, t0));
}

__global__ __launch_bounds__(256) void k_fullspec(const float* __restrict__ p, float* __restrict__ fs)
{
  int idx = blockIdx.x * 256 + threadIdx.x;
  if (idx >= BATCH * FH * FW) return;
  int b = idx >> 16;
  int h = (idx >> 9) & (FH - 1);
  int w = idx & (FW - 1);
  fs[idx] = fs_at(p + b * (GH * GW), h, w);
}

__global__ __launch_bounds__(256) void k_mag(const float* __restrict__ p, float* __restrict__ mag)
{
  int idx = blockIdx.x * 256 + threadIdx.x;
  if (idx >= NMAG) return;
  int b = idx / (NW * NFREQ);
  int rem = idx - b * (NW * NFREQ);
  int f = rem / NFREQ;
  int k = rem - f * NFREQ;
  const float* pb = p + b * (GH * GW);
  int h0, h1; float wa, wb;
  lin_taps(sf_H2(k), FH, h0, h1, wa, wb);
  float fs0 = fs_at(pb, h0, f);
  float fs1 = fs_at(pb, h1, f);
  float P0 = __fmul_rn(__fmul_rn(fs0, fs0), 100.0f);
  float P1 = __fmul_rn(__fmul_rn(fs1, fs1), 100.0f);
  float lin = __fmaf_rn(wb, P1, __fmul_rn(wa, P0));
  mag[idx] = __fsqrt_rn(fmaxf(lin, 0.0f));
}

__global__ __launch_bounds__(256) void k_phase(float2* __restrict__ ang)
{
  int idx = blockIdx.x * 256 + threadIdx.x;
  if (idx >= NMAG) return;
  int b = idx / (NW * NFREQ);
  int rem = idx - b * (NW * NFREQ);
  int f = rem / NFREQ;
  int k = rem - f * NFREQ;
  u32 cnt = (u32)(b * (NFREQ * NW) + k * NW + f);  // flat index in (B,513,512) C-order
  u32 w0, w1;
  threefry2(0u, cnt, w0, w1);
  u32 bits = w0 ^ w1;
  float u = __uint_as_float((bits >> 9) | 0x3f800000u) - 1.0f;
  float th = __fmul_rn((float)6.283185307179586, u);
  double thd = (double)th;
  ang[idx] = make_float2((float)cos(thd), (float)sin(thd));
}

// ---------------- 512-pt complex FFT: radix-4 Stockham, PING-PONG LDS, f32 core ----------------
// f32 matches jax's complex64 FFT precision class. Twiddles w1,w2,w3 gathered from a
// 0.5-ulp f32 table (w2 = e^{-2pi i 2base/512} etc., indices < 512 so no wrap needed).
template<bool INV, int S4>
__device__ __forceinline__ void fft512_stage(const float2* __restrict__ Sb,
                                             float2* __restrict__ Db,
                                             const float2* __restrict__ tw, int t)
{
  const int L = 1 << (2 * S4);
  const int m = 128 >> (2 * S4);
  int p = t >> (2 * S4);
  int q = t & (L - 1);
  float2 x0 = Sb[SL(q + (p)         * L)];
  float2 x1 = Sb[SL(q + (p + m)     * L)];
  float2 x2 = Sb[SL(q + (p + 2 * m) * L)];
  float2 x3 = Sb[SL(q + (p + 3 * m) * L)];
  float t0x = x0.x + x2.x, t0y = x0.y + x2.y;
  float t1x = x0.x - x2.x, t1y = x0.y - x2.y;
  float t2x = x1.x + x3.x, t2y = x1.y + x3.y;
  float t3x = x1.x - x3.x, t3y = x1.y - x3.y;
  float y0x = t0x + t2x, y0y = t0y + t2y;
  float y2x = t0x - t2x, y2y = t0y - t2y;
  float y1x, y1y, y3x, y3y;
  if (INV) { y1x = t1x - t3y; y1y = t1y + t3x; y3x = t1x + t3y; y3y = t1y - t3x; }
  else     { y1x = t1x + t3y; y1y = t1y - t3x; y3x = t1x - t3y; y3y = t1y + t3x; }
  int base = p << (2 * S4);                 // <= 127 always
  float2 w1 = tw[base];
  float2 w2 = tw[(2 * base) & 511];
  float2 w3 = tw[(3 * base) & 511];
  float w1y = INV ? -w1.y : w1.y;
  float w2y = INV ? -w2.y : w2.y;
  float w3y = INV ? -w3.y : w3.y;
  float2 o0; o0.x = y0x; o0.y = y0y;
  float2 o1; o1.x = y1x * w1.x - y1y * w1y; o1.y = y1x * w1y + y1y * w1.x;
  float2 o2; o2.x = y2x * w2.x - y2y * w2y; o2.y = y2x * w2y + y2y * w2.x;
  float2 o3; o3.x = y3x * w3.x - y3y * w3y; o3.y = y3x * w3y + y3y * w3.x;
  int ob = q + (4 * p) * L;
  Db[SL(ob)]         = o0;
  Db[SL(ob + L)]     = o1;
  Db[SL(ob + 2 * L)] = o2;
  Db[SL(ob + 3 * L)] = o3;
}

// 4 radix-4 stages, ping-pong A->B->A->B->A. Caller must barrier before (A fully packed).
// Result lands back in A.
template<bool INV>
__device__ __forceinline__ void fft512_pp(float2* __restrict__ A, float2* __restrict__ B,
                                          const float2* __restrict__ tw, int t)
{
  fft512_stage<INV, 0>(A, B, tw, t); __syncthreads();
  fft512_stage<INV, 1>(B, A, tw, t); __syncthreads();
  fft512_stage<INV, 2>(A, B, tw, t); __syncthreads();
  fft512_stage<INV, 3>(B, A, tw, t); __syncthreads();
}

// forward final radix-2: read A, write B (caller barriers after; spectrum then in B)
__device__ __forceinline__ void fwd_radix2(const float2* __restrict__ A, float2* __restrict__ B, int t)
{
  float2 a0 = A[SL(t)];
  float2 a1 = A[SL(t + 256)];
  float2 b0 = A[SL(t + 128)];
  float2 b1 = A[SL(t + 384)];
  float2 e0; e0.x = a0.x + a1.x; e0.y = a0.y + a1.y;
  float2 d0; d0.x = a0.x - a1.x; d0.y = a0.y - a1.y;
  float2 e1; e1.x = b0.x + b1.x; e1.y = b0.y + b1.y;
  float2 d1; d1.x = b0.x - b1.x; d1.y = b0.y - b1.y;
  B[SL(t)]       = e0;
  B[SL(t + 256)] = d0;
  B[SL(t + 128)] = e1;
  B[SL(t + 384)] = d1;
}

// inverse tail: final radix-2 entirely in registers (thread t owns outputs t, t+128, t+256, t+384)
// then scale (exact *2^-9) + window + store.
__device__ __forceinline__ void ifft_tail_store(const float2* __restrict__ A, int t,
                                                const float* __restrict__ win,
                                                float* __restrict__ frow)
{
  float2 a0 = A[SL(t)];
  float2 a1 = A[SL(t + 256)];
  float2 b0 = A[SL(t + 128)];
  float2 b1 = A[SL(t + 384)];
  const float s = 1.0f / 512.0f;           // exact power of two
  {
    int m = t;                       // e0 = a0 + a1
    float xr = __fmul_rn(__fadd_rn(a0.x, a1.x), s);
    float xi = __fmul_rn(__fadd_rn(a0.y, a1.y), s);
    frow[2 * m]     = __fmul_rn(xr, win[2 * m]);
    frow[2 * m + 1] = __fmul_rn(xi, win[2 * m + 1]);
  }
  {
    int m = t + 128;                 // e1 = b0 + b1
    float xr = __fmul_rn(__fadd_rn(b0.x, b1.x), s);
    float xi = __fmul_rn(__fadd_rn(b0.y, b1.y), s);
    frow[2 * m]     = __fmul_rn(xr, win[2 * m]);
    frow[2 * m + 1] = __fmul_rn(xi, win[2 * m + 1]);
  }
  {
    int m = t + 256;                 // d0 = a0 - a1
    float xr = __fmul_rn(__fsub_rn(a0.x, a1.x), s);
    float xi = __fmul_rn(__fsub_rn(a0.y, a1.y), s);
    frow[2 * m]     = __fmul_rn(xr, win[2 * m]);
    frow[2 * m + 1] = __fmul_rn(xi, win[2 * m + 1]);
  }
  {
    int m = t + 384;                 // d1 = b0 - b1
    float xr = __fmul_rn(__fsub_rn(b0.x, b1.x), s);
    float xi = __fmul_rn(__fsub_rn(b0.y, b1.y), s);
    frow[2 * m]     = __fmul_rn(xr, win[2 * m]);
    frow[2 * m + 1] = __fmul_rn(xi, win[2 * m + 1]);
  }
}

// ---------------- initial ISTFT: irfft(1024) of mag*ang(global) via ifft(512), *win ----------------
__global__ __launch_bounds__(128) void k_istft(const float* __restrict__ mag, const float2* __restrict__ ang,
                                               float* __restrict__ frames,
                                               const float2* __restrict__ tw512f,
                                               const double2* __restrict__ twh,
                                               const float* __restrict__ win)
{
  __shared__ float2 bufA[LDSN];
  __shared__ float2 bufB[LDSN];
  int bf = blockIdx.x;          // b*512 + f
  int t = threadIdx.x;
  const float*  mrow = mag + bf * NFREQ;
  const float2* arow = ang + bf * NFREQ;
  for (int k = t; k < 512; k += 128) {
    float m1 = mrow[k];       float2 a1 = arow[k];
    int k2 = 512 - k;
    float m2 = mrow[k2];      float2 a2 = arow[k2];
    float S1x = __fmul_rn(m1, a1.x), S1y = __fmul_rn(m1, a1.y);
    float S2x = __fmul_rn(m2, a2.x), S2y = __fmul_rn(m2, a2.y);
    double Zx, Zy;
    if (k == 0) {
      Zx = 0.5 * ((double)S1x + (double)S2x);
      Zy = 0.5 * ((double)S1x - (double)S2x);
    } else {
      double Xex = 0.5 * ((double)S1x + (double)S2x);
      double Xey = 0.5 * ((double)S1y - (double)S2y);
      double Dx  = 0.5 * ((double)S1x - (double)S2x);
      double Dy  = 0.5 * ((double)S1y + (double)S2y);
      double2 w = twh[k];                  // e^{-2pi i k/1024}
      double ux = w.x * Dx + w.y * Dy;     // conj(w)*D
      double uy = w.x * Dy - w.y * Dx;
      Zx = Xex - uy;
      Zy = Xey + ux;
    }
    bufA[SL(k)] = make_float2((float)Zx, (float)Zy);
  }
  __syncthreads();
  fft512_pp<true>(bufA, bufB, tw512f, t);   // result in bufA
  ifft_tail_store(bufA, t, win, frames + bf * NFFT);
}

// f32 OLA sample at wsq-coordinate j
__device__ __forceinline__ float sig_sample(const float* __restrict__ fb, const float* __restrict__ wsq, int j)
{
  int gmax = j >> 8; if (gmax > NW - 1) gmax = NW - 1;
  int gmin = (j >= NFFT) ? ((j - (NFFT - 1) + 255) >> 8) : 0;
  float acc = 0.f;
  for (int g = gmin; g <= gmax; ++g)
    acc = __fadd_rn(acc, fb[g * NFFT + (j - (g << 8))]);
  float wv = wsq[j];
  return __fdiv_rn(acc, wv > 1e-11f ? wv : 1.0f);
}

// ---------------- per-iteration: OLA + reflect-pad -> xp[b][0..TOTAL_LEN) ----------------
__global__ __launch_bounds__(256) void k_sig(const float* __restrict__ frames, const float* __restrict__ wsq,
                                             float* __restrict__ xp)
{
  int idx = blockIdx.x * 256 + threadIdx.x;   // < BATCH*TOTAL_LEN
  int b = idx / TOTAL_LEN;
  int j = idx - b * TOTAL_LEN;
  int n = j - 512;
  if (n < 0) n = -n;
  if (n >= SIGLEN) n = 2 * SIGLEN - 2 - n;
  xp[idx] = sig_sample(frames + b * (NW * NFFT), wsq, n + 512);
}

// ---------------- FUSED: stft_it (+ phase update in LDS) + istft_{it+1} ----------------
// angL overlays the dead bufA region during the epilogue (bufA's content was consumed by
// fwd_radix2 before the overlay is written; inverse restarts by packing into bufB).
__global__ __launch_bounds__(128) void k_fused(const float* __restrict__ xp,
                                               const float* __restrict__ win,
                                               const float2* __restrict__ tw512f,
                                               const double2* __restrict__ twh,
                                               const float* __restrict__ mag,
                                               float2* __restrict__ tprev,
                                               float* __restrict__ frames)
{
  __shared__ float2 bufA[LDSN];
  __shared__ float2 bufB[LDSN];
  float2* angL = (float2*)bufA;     // 513 float2 = 4104 B <= 4608 B
  int bf = blockIdx.x;
  int b = bf >> 9;
  int f = bf & (NW - 1);
  int t = threadIdx.x;

  // ---- forward: pack two real samples per complex point ----
  const float* xrow = xp + b * TOTAL_LEN + f * HOP;
  for (int m = t; m < 512; m += 128) {
    float s0 = __fmul_rn(xrow[2 * m],     win[2 * m]);
    float s1 = __fmul_rn(xrow[2 * m + 1], win[2 * m + 1]);
    bufA[SL(m)] = make_float2(s0, s1);
  }
  __syncthreads();
  fft512_pp<false>(bufA, bufB, tw512f, t);  // result in bufA
  fwd_radix2(bufA, bufB, t);                // spectrum -> bufB
  __syncthreads();

  // ---- unpack rfft bins + momentum phase update (f64 boundary combine, f32 quantize) ----
  // reads bufB (spectrum), writes angL (overlaid on now-dead bufA)
  float2* prow = tprev + bf * NFREQ;
  const float cf = (float)(0.99 / 1.99);
  for (int k = t; k < NFREQ; k += 128) {
    double rx, ry;
    if (k == 0)        { rx = (double)bufB[SL(0)].x + (double)bufB[SL(0)].y; ry = 0.0; }
    else if (k == 512) { rx = (double)bufB[SL(0)].x - (double)bufB[SL(0)].y; ry = 0.0; }
    else {
      float2 Zk = bufB[SL(k)];
      float2 Zc = bufB[SL(512 - k)];
      double Xex = 0.5 * ((double)Zk.x + (double)Zc.x);
      double Xey = 0.5 * ((double)Zk.y - (double)Zc.y);
      double Gx  = 0.5 * ((double)Zk.x - (double)Zc.x);
      double Gy  = 0.5 * ((double)Zk.y + (double)Zc.y);
      double Xox = Gy, Xoy = -Gx;          // Xo = -i*G
      double2 w = twh[k];
      rx = Xex + (w.x * Xox - w.y * Xoy);  // S = Xe + w*Xo
      ry = Xey + (w.x * Xoy + w.y * Xox);
    }
    float rxf = (float)rx, ryf = (float)ry;  // rfft quantized to c64
    float2 pv = prow[k];
    float ax = __fsub_rn(rxf, __fmul_rn(pv.x, cf));
    float ay = __fsub_rn(ryf, __fmul_rn(pv.y, cf));
    double dx = (double)ax, dy = (double)ay;
    float d = (float)sqrt(dx * dx + dy * dy);   // np.abs(c64) = hypotf
    float d2 = __fadd_rn(d, 1e-16f);
    float inv = __fdiv_rn(1.0f, d2);
    angL[k] = make_float2(__fmul_rn(ax, inv), __fmul_rn(ay, inv));
    prow[k] = make_float2(rxf, ryf);
  }
  __syncthreads();   // angL complete; all reads of bufB spectrum done

  // ---- inverse: Hermitian pack mag*angL into bufB ----
  const float* mrow = mag + bf * NFREQ;
  for (int k = t; k < 512; k += 128) {
    float m1 = mrow[k];       float2 a1 = angL[k];
    int k2 = 512 - k;
    float m2 = mrow[k2];      float2 a2 = angL[k2];
    float S1x = __fmul_rn(m1, a1.x), S1y = __fmul_rn(m1, a1.y);
    float S2x = __fmul_rn(m2, a2.x), S2y = __fmul_rn(m2, a2.y);
    double Zx, Zy;
    if (k == 0) {
      Zx = 0.5 * ((double)S1x + (double)S2x);
      Zy = 0.5 * ((double)S1x - (double)S2x);
    } else {
      double Xex = 0.5 * ((double)S1x + (double)S2x);
      double Xey = 0.5 * ((double)S1y - (double)S2y);
      double Dx  = 0.5 * ((double)S1x - (double)S2x);
      double Dy  = 0.5 * ((double)S1y + (double)S2y);
      double2 w = twh[k];
      double ux = w.x * Dx + w.y * Dy;
      double uy = w.x * Dy - w.y * Dx;
      Zx = Xex - uy;
      Zy = Xey + ux;
    }
    bufB[SL(k)] = make_float2((float)Zx, (float)Zy);
  }
  __syncthreads();
  fft512_pp<true>(bufB, bufA, tw512f, t);   // result in bufB (angL region destroyed - OK)
  ifft_tail_store(bufB, t, win, frames + bf * NFFT);
}

// ---------------- final OLA -> audio f32 + fused per-block |max| reduction ----------------
__global__ __launch_bounds__(256) void k_ola(const float* __restrict__ frames, const float* __restrict__ wsq,
                                             float* __restrict__ audio, float* __restrict__ partial)
{
  int idx = blockIdx.x * 256 + threadIdx.x;  // < BATCH*NSAMP
  int b  = idx >> 17;
  int nn = idx & (NSAMP - 1);
  float v = 0.f;
  if (nn < SIGLEN)
    v = sig_sample(frames + b * (NW * NFFT), wsq, nn + 512);
  audio[idx] = v;
  __shared__ float red[256];
  red[threadIdx.x] = fabsf(v);
  __syncthreads();
  for (int s = 128; s > 0; s >>= 1) {
    if (threadIdx.x < s) red[threadIdx.x] = fmaxf(red[threadIdx.x], red[threadIdx.x + s]);
    __syncthreads();
  }
  if (threadIdx.x == 0) partial[blockIdx.x] = red[0];   // 512 partials per batch
}

constexpr int OLA_BLK_PER_B = NSAMP / 256;   // 512

__global__ __launch_bounds__(256) void k_max2(const float* __restrict__ partial, float* __restrict__ maxbuf)
{
  int b = blockIdx.x;
  float m = 0.f;
  for (int i = threadIdx.x; i < OLA_BLK_PER_B; i += 256)
    m = fmaxf(m, partial[b * OLA_BLK_PER_B + i]);
  __shared__ float red[256];
  red[threadIdx.x] = m;
  __syncthreads();
  for (int s = 128; s > 0; s >>= 1) {
    if (threadIdx.x < s) red[threadIdx.x] = fmaxf(red[threadIdx.x], red[threadIdx.x + s]);
    __syncthreads();
  }
  if (threadIdx.x == 0) maxbuf[b] = red[0];
}

__global__ __launch_bounds__(256) void k_norm(const float* __restrict__ audio, const float* __restrict__ maxbuf,
                                              float* __restrict__ out)
{
  int idx = blockIdx.x * 256 + threadIdx.x;
  int b = idx >> 17;
  float m = fmaxf(maxbuf[b], 1e-8f);
  out[idx] = __fmul_rn(__fdiv_rn(audio[idx], m), 0.9f);
}

extern "C" void kernel_launch(void* const* d_in, const int* in_sizes, int n_in,
                              void* d_out, int out_size, void* d_ws, size_t ws_size,
                              hipStream_t stream)
{
  const float* params = (const float*)d_in[0];
  float* out   = (float*)d_out;
  float* audio_out = out;                   // BATCH*NSAMP
  float* fs        = out + BATCH * NSAMP;   // BATCH*FH*FW (full_spec output)

  // workspace layout (16B-aligned first)
  float2*  tw512f = (float2*)d_ws;                         // 512 (4KB)
  double2* twh    = (double2*)(tw512f + 512);              // 512 (8KB, 16B aligned)
  float2*  ang    = (float2*)(twh + 512);                  // NMAG c64 (initial phases only)
  float2*  tprev  = ang + NMAG;                            // NMAG c64
  float*   frames = (float*)(tprev + NMAG);                // BATCH*NW*NFFT f32
  float*   mag    = frames + BATCH * NW * NFFT;            // NMAG f32
  float*   xp     = mag + NMAG;                            // BATCH*TOTAL_LEN f32
  float*   win    = xp + BATCH * TOTAL_LEN;                // NFFT
  float*   wsq    = win + NFFT;                            // TOTAL_LEN
  float*   audio32= wsq + TOTAL_LEN;                       // BATCH*NSAMP
  float*   maxbuf = audio32 + BATCH * NSAMP;               // BATCH
  float*   partial= maxbuf + BATCH;                        // BATCH*OLA_BLK_PER_B

  k_init<<<512, 256, 0, stream>>>(win, tw512f, twh, wsq, tprev);
  k_fullspec<<<(BATCH * FH * FW) / 256, 256, 0, stream>>>(params, fs);
  k_mag<<<(NMAG + 255) / 256, 256, 0, stream>>>(params, mag);
  k_phase<<<(NMAG + 255) / 256, 256, 0, stream>>>(ang);

  // istft0 with initial phases, then 32x [OLA->xp ; fused stft+update+istft]
  k_istft<<<BATCH * NW, 128, 0, stream>>>(mag, (const float2*)ang, frames, tw512f, twh, win);
  for (int it = 0; it < NITER; ++it) {
    k_sig<<<(BATCH * TOTAL_LEN) / 256, 256, 0, stream>>>(frames, wsq, xp);
    k_fused<<<BATCH * NW, 128, 0, stream>>>(xp, win, tw512f, twh, mag, tprev, frames);
  }
  k_ola<<<(BATCH * NSAMP) / 256, 256, 0, stream>>>(frames, wsq, audio32, partial);
  k_max2<<<BATCH, 256, 0, stream>>>(partial, maxbuf);
  k_norm<<<(BATCH * NSAMP) / 256, 256, 0, stream>>>(audio32, maxbuf, audio_out);
}

// Round 5
// 919.840 us; speedup vs baseline: 1.7116x; 1.3051x over previous
//
#include <hip/hip_runtime.h>

typedef unsigned int u32;

constexpr int BATCH = 8;
constexpr int GH = 32, GW = 64;
constexpr int FH = 128, FW = 512;
constexpr int NFFT = 1024;
constexpr int HOP = 256;
constexpr int NFREQ = 513;
constexpr int NW = 512;                       // frames per batch
constexpr int SIGLEN = HOP * (NW - 1);        // 130816
constexpr int TOTAL_LEN = NFFT + HOP*(NW-1);  // 131840
constexpr int NITER = 32;
constexpr int NSAMP = 131072;
constexpr int NMAG = BATCH * NW * NFREQ;      // 2101248

// LDS index padding (9/8 stride)
#define SL(i) ((i) + ((i) >> 3))
constexpr int WSL = 576;    // per-wave LDS slots: SL(511)=574, slot 575 = bin-512 home

#define WAVEFENCE() __builtin_amdgcn_wave_barrier()

// ---------------- Threefry-2x32-20, partitionable path (key = (0,1)) ----------------
__device__ __forceinline__ void tf_round(u32 &x0, u32 &x1, int r) {
  x0 += x1;
  x1 = (x1 << r) | (x1 >> (32 - r));
  x1 ^= x0;
}

__device__ __forceinline__ void threefry2(u32 c0, u32 c1, u32 &o0, u32 &o1) {
  const u32 k0 = 0u, k1 = 1u;
  const u32 k2 = 0x1BD11BDAu ^ k0 ^ k1;
  u32 x0 = c0 + k0, x1 = c1 + k1;
  tf_round(x0, x1, 13); tf_round(x0, x1, 15); tf_round(x0, x1, 26); tf_round(x0, x1, 6);
  x0 += k1; x1 += k2 + 1u;
  tf_round(x0, x1, 17); tf_round(x0, x1, 29); tf_round(x0, x1, 16); tf_round(x0, x1, 24);
  x0 += k2; x1 += k0 + 2u;
  tf_round(x0, x1, 13); tf_round(x0, x1, 15); tf_round(x0, x1, 26); tf_round(x0, x1, 6);
  x0 += k0; x1 += k1 + 3u;
  tf_round(x0, x1, 17); tf_round(x0, x1, 29); tf_round(x0, x1, 16); tf_round(x0, x1, 24);
  x0 += k1; x1 += k2 + 4u;
  tf_round(x0, x1, 13); tf_round(x0, x1, 15); tf_round(x0, x1, 26); tf_round(x0, x1, 6);
  x0 += k2; x1 += k0 + 5u;
  o0 = x0; o1 = x1;
}

// ---------------- init ----------------
__global__ __launch_bounds__(256) void k_init(float* __restrict__ win,
                                              float2* __restrict__ tw512f, double2* __restrict__ twh,
                                              float* __restrict__ wsq,
                                              float2* __restrict__ tprev)
{
  int idx = blockIdx.x * 256 + threadIdx.x;
  int stride = gridDim.x * 256;
  const double PI2 = 6.283185307179586476925286766559;
  for (int t = idx; t < NFFT; t += stride)
    win[t] = (float)(0.5 * (1.0 - cos(PI2 * (double)t / 1024.0)));  // _WIN f32
  for (int k = idx; k < 512; k += stride) {
    double th = -PI2 * (double)k / 512.0;
    tw512f[k] = make_float2((float)cos(th), (float)sin(th));  // e^{-2pi i k/512}
    double th2 = -PI2 * (double)k / 1024.0;
    double2 v2; v2.x = cos(th2); v2.y = sin(th2);
    twh[k] = v2;                                      // e^{-2pi i k/1024} (f64 boundary)
  }
  for (int j = idx; j < TOTAL_LEN; j += stride) {
    int gmax = j >> 8; if (gmax > NW - 1) gmax = NW - 1;
    int gmin = (j >= NFFT) ? ((j - (NFFT - 1) + 255) >> 8) : 0;
    float acc = 0.f;
    for (int g = gmin; g <= gmax; ++g) {
      float w = (float)(0.5 * (1.0 - cos(PI2 * (double)(j - (g << 8)) / 1024.0)));
      acc = __fadd_rn(acc, __fmul_rn(w, w));
    }
    wsq[j] = acc;
  }
  for (int i = idx; i < NMAG; i += stride)
    tprev[i] = make_float2(0.f, 0.f);
}

// ---------------- jax.image.resize bilinear ----------------
__device__ __forceinline__ void lin_taps(float sf, int in, int &i0, int &i1, float &w0, float &w1)
{
  if (sf <= 0.0f)                  { i0 = 0;      i1 = 0;      w0 = 1.0f; w1 = 0.0f; return; }
  if (sf >= (float)(in - 1))       { i0 = in - 1; i1 = in - 1; w0 = 1.0f; w1 = 0.0f; return; }
  i0 = (int)sf; i1 = i0 + 1;
  float x0 = __fsub_rn(sf, (float)i0);
  float a0 = __fsub_rn(1.0f, x0);
  float S  = __fadd_rn(a0, x0);
  w0 = __fdiv_rn(a0, S);
  w1 = __fdiv_rn(x0, S);
}

__device__ __forceinline__ float sf_H1(int H) {
  return __fadd_rn(__fmul_rn(__fadd_rn((float)H, 0.5f), 0.25f), -0.5f);
}
__device__ __forceinline__ float sf_W1(int W) {
  return __fadd_rn(__fmul_rn(__fadd_rn((float)W, 0.5f), 0.125f), -0.5f);
}
__device__ __forceinline__ float sf_H2(int K) {
  const float inv32 = (float)(1.0 / 4.0078125);
  return __fadd_rn(__fmul_rn(__fadd_rn((float)K, 0.5f), inv32), -0.5f);
}

__device__ __forceinline__ float fs_at(const float* __restrict__ pb, int H, int W)
{
  int r0, r1; float u0, u1;
  lin_taps(sf_H1(H), GH, r0, r1, u0, u1);
  int c0, c1; float v0, v1;
  lin_taps(sf_W1(W), GW, c0, c1, v0, v1);
  float t0 = __fmaf_rn(u1, pb[r1 * GW + c0], __fmul_rn(u0, pb[r0 * GW + c0]));
  float t1 = __fmaf_rn(u1, pb[r1 * GW + c1], __fmul_rn(u0, pb[r0 * GW + c1]));
  return __fmaf_rn(v1, t1, __fmul_rn(v0, t0));
}

__global__ __launch_bounds__(256) void k_fullspec(const float* __restrict__ p, float* __restrict__ fs)
{
  int idx = blockIdx.x * 256 + threadIdx.x;
  if (idx >= BATCH * FH * FW) return;
  int b = idx >> 16;
  int h = (idx >> 9) & (FH - 1);
  int w = idx & (FW - 1);
  fs[idx] = fs_at(p + b * (GH * GW), h, w);
}

__global__ __launch_bounds__(256) void k_mag(const float* __restrict__ p, float* __restrict__ mag)
{
  int idx = blockIdx.x * 256 + threadIdx.x;
  if (idx >= NMAG) return;
  int b = idx / (NW * NFREQ);
  int rem = idx - b * (NW * NFREQ);
  int f = rem / NFREQ;
  int k = rem - f * NFREQ;
  const float* pb = p + b * (GH * GW);
  int h0, h1; float wa, wb;
  lin_taps(sf_H2(k), FH, h0, h1, wa, wb);
  float fs0 = fs_at(pb, h0, f);
  float fs1 = fs_at(pb, h1, f);
  float P0 = __fmul_rn(__fmul_rn(fs0, fs0), 100.0f);
  float P1 = __fmul_rn(__fmul_rn(fs1, fs1), 100.0f);
  float lin = __fmaf_rn(wb, P1, __fmul_rn(wa, P0));
  mag[idx] = __fsqrt_rn(fmaxf(lin, 0.0f));
}

__global__ __launch_bounds__(256) void k_phase(float2* __restrict__ ang)
{
  int idx = blockIdx.x * 256 + threadIdx.x;
  if (idx >= NMAG) return;
  int b = idx / (NW * NFREQ);
  int rem = idx - b * (NW * NFREQ);
  int f = rem / NFREQ;
  int k = rem - f * NFREQ;
  u32 cnt = (u32)(b * (NFREQ * NW) + k * NW + f);
  u32 w0, w1;
  threefry2(0u, cnt, w0, w1);
  u32 bits = w0 ^ w1;
  float u = __uint_as_float((bits >> 9) | 0x3f800000u) - 1.0f;
  float th = __fmul_rn((float)6.283185307179586, u);
  double thd = (double)th;
  ang[idx] = make_float2((float)cos(thd), (float)sin(thd));
}

// ---------------- 512-pt FFT: radix-8^3 Stockham, ONE WAVE per transform, NO s_barriers ----------------
// 64 lanes x 8 points. In-place stages are safe because a wave issues its DS ops in program
// order (all stage reads precede all stage writes); WAVEFENCE() makes the read/write phase
// boundary explicit to the compiler scheduler (zero runtime cost).
__device__ __forceinline__ float2 cadd2(float2 a, float2 b){ return make_float2(a.x+b.x, a.y+b.y); }
__device__ __forceinline__ float2 csub2(float2 a, float2 b){ return make_float2(a.x-b.x, a.y-b.y); }

template<bool INV>
__device__ __forceinline__ float2 twmul(float2 a, float2 w)
{
  float wy = INV ? -w.y : w.y;
  return make_float2(a.x*w.x - a.y*wy, a.x*wy + a.y*w.x);
}

template<bool INV>
__device__ __forceinline__ void bfly8(float2 x0, float2 x1, float2 x2, float2 x3,
                                      float2 x4, float2 x5, float2 x6, float2 x7,
                                      float2 &Y0, float2 &Y1, float2 &Y2, float2 &Y3,
                                      float2 &Y4, float2 &Y5, float2 &Y6, float2 &Y7)
{
  const float c = 0.70710678118654752440f;
  float2 u0 = cadd2(x0,x4), u1 = cadd2(x1,x5), u2 = cadd2(x2,x6), u3 = cadd2(x3,x7);
  float2 d0 = csub2(x0,x4), d1 = csub2(x1,x5), d2 = csub2(x2,x6), d3 = csub2(x3,x7);
  float2 w1, w2, w3;
  if (!INV) {
    w1 = make_float2(c*(d1.x + d1.y), c*(d1.y - d1.x));   // x w8^1 = (c,-c)
    w2 = make_float2(d2.y, -d2.x);                        // x (-i)
    w3 = make_float2(c*(d3.y - d3.x), -c*(d3.x + d3.y));  // x w8^3 = (-c,-c)
  } else {
    w1 = make_float2(c*(d1.x - d1.y), c*(d1.x + d1.y));   // x (c,c)
    w2 = make_float2(-d2.y, d2.x);                        // x (+i)
    w3 = make_float2(-c*(d3.x + d3.y), c*(d3.x - d3.y));  // x (-c,c)
  }
  float2 s0 = cadd2(u0,u2), s1 = cadd2(u1,u3), s2 = csub2(u0,u2);
  float2 e13 = csub2(u1,u3);
  float2 s3 = INV ? make_float2(-e13.y, e13.x) : make_float2(e13.y, -e13.x);
  float2 r0 = cadd2(d0,w2), r1 = cadd2(w1,w3), r2 = csub2(d0,w2);
  float2 e57 = csub2(w1,w3);
  float2 r3 = INV ? make_float2(-e57.y, e57.x) : make_float2(e57.y, -e57.x);
  Y0 = cadd2(s0,s1); Y4 = csub2(s0,s1);
  Y2 = cadd2(s2,s3); Y6 = csub2(s2,s3);
  Y1 = cadd2(r0,r1); Y5 = csub2(r0,r1);
  Y3 = cadd2(r2,r3); Y7 = csub2(r2,r3);
}

// stage 0: inputs in registers, twiddle base = t, write slots 8t+k
template<bool INV>
__device__ __forceinline__ void stage0_regs(float2* __restrict__ A, const float2* __restrict__ tw, int t,
    float2 x0, float2 x1, float2 x2, float2 x3, float2 x4, float2 x5, float2 x6, float2 x7)
{
  float2 Y0,Y1,Y2,Y3,Y4,Y5,Y6,Y7;
  bfly8<INV>(x0,x1,x2,x3,x4,x5,x6,x7, Y0,Y1,Y2,Y3,Y4,Y5,Y6,Y7);
  int ob = 8 * t;
  A[SL(ob + 0)] = Y0;
  A[SL(ob + 1)] = twmul<INV>(Y1, tw[t]);
  A[SL(ob + 2)] = twmul<INV>(Y2, tw[2 * t]);
  A[SL(ob + 3)] = twmul<INV>(Y3, tw[3 * t]);
  A[SL(ob + 4)] = twmul<INV>(Y4, tw[4 * t]);
  A[SL(ob + 5)] = twmul<INV>(Y5, tw[5 * t]);
  A[SL(ob + 6)] = twmul<INV>(Y6, tw[6 * t]);
  A[SL(ob + 7)] = twmul<INV>(Y7, tw[7 * t]);
}

// stage 1 (L=8): in-place LDS->LDS, twiddle base = 8p, write slots q+64p+8k
template<bool INV>
__device__ __forceinline__ void stage_mid(float2* __restrict__ A, const float2* __restrict__ tw, int t)
{
  float2 x0 = A[SL(t)],       x1 = A[SL(t + 64)],  x2 = A[SL(t + 128)], x3 = A[SL(t + 192)];
  float2 x4 = A[SL(t + 256)], x5 = A[SL(t + 320)], x6 = A[SL(t + 384)], x7 = A[SL(t + 448)];
  float2 Y0,Y1,Y2,Y3,Y4,Y5,Y6,Y7;
  bfly8<INV>(x0,x1,x2,x3,x4,x5,x6,x7, Y0,Y1,Y2,Y3,Y4,Y5,Y6,Y7);
  WAVEFENCE();
  int p = t >> 3, q = t & 7;
  int base = 8 * p;
  int ob = q + 64 * p;
  A[SL(ob)]      = Y0;
  A[SL(ob + 8)]  = twmul<INV>(Y1, tw[base]);
  A[SL(ob + 16)] = twmul<INV>(Y2, tw[2 * base]);
  A[SL(ob + 24)] = twmul<INV>(Y3, tw[3 * base]);
  A[SL(ob + 32)] = twmul<INV>(Y4, tw[4 * base]);
  A[SL(ob + 40)] = twmul<INV>(Y5, tw[5 * base]);
  A[SL(ob + 48)] = twmul<INV>(Y6, tw[6 * base]);
  A[SL(ob + 56)] = twmul<INV>(Y7, tw[7 * base]);
}

// stage 2 (L=64, base=0): lane-local in-place, result natural order A[t+64k]
template<bool INV>
__device__ __forceinline__ void stage_last_lds(float2* __restrict__ A, int t)
{
  float2 x0 = A[SL(t)],       x1 = A[SL(t + 64)],  x2 = A[SL(t + 128)], x3 = A[SL(t + 192)];
  float2 x4 = A[SL(t + 256)], x5 = A[SL(t + 320)], x6 = A[SL(t + 384)], x7 = A[SL(t + 448)];
  float2 Y0,Y1,Y2,Y3,Y4,Y5,Y6,Y7;
  bfly8<INV>(x0,x1,x2,x3,x4,x5,x6,x7, Y0,Y1,Y2,Y3,Y4,Y5,Y6,Y7);
  WAVEFENCE();
  A[SL(t)]       = Y0; A[SL(t + 64)]  = Y1; A[SL(t + 128)] = Y2; A[SL(t + 192)] = Y3;
  A[SL(t + 256)] = Y4; A[SL(t + 320)] = Y5; A[SL(t + 384)] = Y6; A[SL(t + 448)] = Y7;
}

// stage 2 -> registers (inverse tail): Yk = time point t+64k
template<bool INV>
__device__ __forceinline__ void stage_last_regs(const float2* __restrict__ A, int t,
    float2 &Y0, float2 &Y1, float2 &Y2, float2 &Y3, float2 &Y4, float2 &Y5, float2 &Y6, float2 &Y7)
{
  float2 x0 = A[SL(t)],       x1 = A[SL(t + 64)],  x2 = A[SL(t + 128)], x3 = A[SL(t + 192)];
  float2 x4 = A[SL(t + 256)], x5 = A[SL(t + 320)], x6 = A[SL(t + 384)], x7 = A[SL(t + 448)];
  bfly8<INV>(x0,x1,x2,x3,x4,x5,x6,x7, Y0,Y1,Y2,Y3,Y4,Y5,Y6,Y7);
}

// momentum phase update for one bin; writes angL (slot-mapped) and tprev
__device__ __forceinline__ void upd_bin(float2* __restrict__ prow, float2* __restrict__ A,
                                        int k, double rx, double ry, float cf)
{
  float rxf = (float)rx, ryf = (float)ry;
  float2 pv = prow[k];
  float ax = __fsub_rn(rxf, __fmul_rn(pv.x, cf));
  float ay = __fsub_rn(ryf, __fmul_rn(pv.y, cf));
  double dx = (double)ax, dy = (double)ay;
  float d = (float)sqrt(dx * dx + dy * dy);
  float d2 = __fadd_rn(d, 1e-16f);
  float inv = __fdiv_rn(1.0f, d2);
  int slot = (k == 512) ? (WSL - 1) : SL(k);
  A[slot] = make_float2(__fmul_rn(ax, inv), __fmul_rn(ay, inv));
  prow[k] = make_float2(rxf, ryf);
}

// ---------------- initial ISTFT: wave-per-frame ----------------
__global__ __launch_bounds__(256) void k_istft(const float* __restrict__ mag, const float2* __restrict__ ang,
                                               float* __restrict__ frames,
                                               const float2* __restrict__ tw512f,
                                               const double2* __restrict__ twh,
                                               const float* __restrict__ win)
{
  __shared__ float2 ldsA[4 * WSL];
  __shared__ float2 twl[512];
  int tid = threadIdx.x;
  for (int i = tid; i < 512; i += 256) twl[i] = tw512f[i];
  __syncthreads();

  int wv = tid >> 6;
  int t  = tid & 63;
  int bf = (blockIdx.x << 2) + wv;
  float2* A = ldsA + wv * WSL;
  const float*  mrow = mag + bf * NFREQ;
  const float2* arow = ang + bf * NFREQ;

  // Hermitian pack straight into registers (points k = t + 64j)
  float2 z0, z1, z2, z3, z4, z5, z6, z7;
#define PACKG(j, zj) { \
    int k = t + 64 * j; \
    if (k == 0) { \
      float m1 = mrow[0];   float2 a1 = arow[0]; \
      float m2 = mrow[512]; float2 a2 = arow[512]; \
      float S1x = __fmul_rn(m1, a1.x); \
      float S2x = __fmul_rn(m2, a2.x); \
      zj = make_float2((float)(0.5 * ((double)S1x + (double)S2x)), \
                       (float)(0.5 * ((double)S1x - (double)S2x))); \
    } else { \
      int k2 = 512 - k; \
      float m1 = mrow[k];  float2 a1 = arow[k]; \
      float m2 = mrow[k2]; float2 a2 = arow[k2]; \
      float S1x = __fmul_rn(m1, a1.x), S1y = __fmul_rn(m1, a1.y); \
      float S2x = __fmul_rn(m2, a2.x), S2y = __fmul_rn(m2, a2.y); \
      double Xex = 0.5 * ((double)S1x + (double)S2x); \
      double Xey = 0.5 * ((double)S1y - (double)S2y); \
      double Dx  = 0.5 * ((double)S1x - (double)S2x); \
      double Dy  = 0.5 * ((double)S1y + (double)S2y); \
      double2 w = twh[k]; \
      double ux = w.x * Dx + w.y * Dy; \
      double uy = w.x * Dy - w.y * Dx; \
      zj = make_float2((float)(Xex - uy), (float)(Xey + ux)); \
    } }
  PACKG(0, z0) PACKG(1, z1) PACKG(2, z2) PACKG(3, z3)
  PACKG(4, z4) PACKG(5, z5) PACKG(6, z6) PACKG(7, z7)

  stage0_regs<true>(A, twl, t, z0, z1, z2, z3, z4, z5, z6, z7);
  WAVEFENCE();
  stage_mid<true>(A, twl, t);
  WAVEFENCE();
  float2 y0, y1, y2, y3, y4, y5, y6, y7;
  stage_last_regs<true>(A, t, y0, y1, y2, y3, y4, y5, y6, y7);

  const float sc = 1.0f / 512.0f;
  const float2* win2 = (const float2*)win;
  float2* frow2 = (float2*)(frames + bf * NFFT);
#define STOREF(k, yk) { int m = t + 64 * k; float2 wv2 = win2[m]; \
    frow2[m] = make_float2(__fmul_rn(__fmul_rn(yk.x, sc), wv2.x), \
                           __fmul_rn(__fmul_rn(yk.y, sc), wv2.y)); }
  STOREF(0, y0) STOREF(1, y1) STOREF(2, y2) STOREF(3, y3)
  STOREF(4, y4) STOREF(5, y5) STOREF(6, y6) STOREF(7, y7)
}

// f32 OLA sample at wsq-coordinate j
__device__ __forceinline__ float sig_sample(const float* __restrict__ fb, const float* __restrict__ wsq, int j)
{
  int gmax = j >> 8; if (gmax > NW - 1) gmax = NW - 1;
  int gmin = (j >= NFFT) ? ((j - (NFFT - 1) + 255) >> 8) : 0;
  float acc = 0.f;
  for (int g = gmin; g <= gmax; ++g)
    acc = __fadd_rn(acc, fb[g * NFFT + (j - (g << 8))]);
  float wv = wsq[j];
  return __fdiv_rn(acc, wv > 1e-11f ? wv : 1.0f);
}

// ---------------- per-iteration: OLA + reflect-pad -> xp ----------------
__global__ __launch_bounds__(256) void k_sig(const float* __restrict__ frames, const float* __restrict__ wsq,
                                             float* __restrict__ xp)
{
  int idx = blockIdx.x * 256 + threadIdx.x;
  int b = idx / TOTAL_LEN;
  int j = idx - b * TOTAL_LEN;
  int n = j - 512;
  if (n < 0) n = -n;
  if (n >= SIGLEN) n = 2 * SIGLEN - 2 - n;
  xp[idx] = sig_sample(frames + b * (NW * NFFT), wsq, n + 512);
}

// ---------------- FUSED: stft + momentum phase + istft, wave-per-frame ----------------
__global__ __launch_bounds__(256) void k_fused(const float* __restrict__ xp,
                                               const float* __restrict__ win,
                                               const float2* __restrict__ tw512f,
                                               const double2* __restrict__ twh,
                                               const float* __restrict__ mag,
                                               float2* __restrict__ tprev,
                                               float* __restrict__ frames)
{
  __shared__ float2 ldsA[4 * WSL];
  __shared__ float2 twl[512];
  int tid = threadIdx.x;
  for (int i = tid; i < 512; i += 256) twl[i] = tw512f[i];
  __syncthreads();

  int wv = tid >> 6;
  int t  = tid & 63;
  int bf = (blockIdx.x << 2) + wv;
  int b = bf >> 9;
  int f = bf & (NW - 1);
  float2* A = ldsA + wv * WSL;
  const float2* win2 = (const float2*)win;

  // ---- forward: windowed pack from global straight into stage 0 ----
  const float2* xrow2 = (const float2*)(xp + b * TOTAL_LEN + f * HOP);
  float2 x0, x1, x2, x3, x4, x5, x6, x7;
#define LOADX(j, xj) { float2 xv = xrow2[t + 64 * j]; float2 wv2 = win2[t + 64 * j]; \
    xj = make_float2(__fmul_rn(xv.x, wv2.x), __fmul_rn(xv.y, wv2.y)); }
  LOADX(0, x0) LOADX(1, x1) LOADX(2, x2) LOADX(3, x3)
  LOADX(4, x4) LOADX(5, x5) LOADX(6, x6) LOADX(7, x7)
  stage0_regs<false>(A, twl, t, x0, x1, x2, x3, x4, x5, x6, x7);
  WAVEFENCE();
  stage_mid<false>(A, twl, t);
  WAVEFENCE();
  stage_last_lds<false>(A, t);   // spectrum Z[k] at A[SL(k)], natural order
  WAVEFENCE();

  // ---- unpack rfft pairs (k, 512-k) + momentum update; angL overlays A in-place ----
  // Each pair (k,512-k) is read AND written by exactly one lane -> no cross-lane hazard here.
  float2* prow = tprev + bf * NFREQ;
  const float cf = (float)(0.99 / 1.99);
#pragma unroll
  for (int j = 0; j < 4; ++j) {
    int k = t + 64 * j;
    if (k == 0) {
      float2 Z0 = A[SL(0)];
      double rx0 = (double)Z0.x + (double)Z0.y;
      double rx5 = (double)Z0.x - (double)Z0.y;
      upd_bin(prow, A, 0,   rx0, 0.0, cf);
      upd_bin(prow, A, 512, rx5, 0.0, cf);
    } else {
      int kc = 512 - k;
      float2 Zk = A[SL(k)];
      float2 Zc = A[SL(kc)];
      double Xex = 0.5 * ((double)Zk.x + (double)Zc.x);
      double Xey = 0.5 * ((double)Zk.y - (double)Zc.y);
      double Gx  = 0.5 * ((double)Zk.x - (double)Zc.x);
      double Gy  = 0.5 * ((double)Zk.y + (double)Zc.y);
      double2 w = twh[k];
      double P = w.x * Gy + w.y * Gx;
      double Q = w.y * Gy - w.x * Gx;
      upd_bin(prow, A, k,  Xex + P, Xey + Q, cf);
      upd_bin(prow, A, kc, Xex - P, Q - Xey, cf);
    }
  }
  if (t == 0) {                      // self-paired bin k = 256
    float2 Zk = A[SL(256)];
    double Xex = 0.5 * ((double)Zk.x + (double)Zk.x);
    double Gy  = 0.5 * ((double)Zk.y + (double)Zk.y);
    double2 w = twh[256];
    double P = w.x * Gy;
    double Q = w.y * Gy;
    upd_bin(prow, A, 256, Xex + P, Q, cf);
  }
  WAVEFENCE();   // angL writes complete before PACKL reads (cross-lane)

  // ---- inverse: Hermitian pack mag*angL (from LDS) into registers, then 3 stages ----
  const float* mrow = mag + bf * NFREQ;
  float2 z0, z1, z2, z3, z4, z5, z6, z7;
#define PACKL(j, zj) { \
    int k = t + 64 * j; \
    if (k == 0) { \
      float m1 = mrow[0];   float2 a1 = A[SL(0)]; \
      float m2 = mrow[512]; float2 a2 = A[WSL - 1]; \
      float S1x = __fmul_rn(m1, a1.x); \
      float S2x = __fmul_rn(m2, a2.x); \
      zj = make_float2((float)(0.5 * ((double)S1x + (double)S2x)), \
                       (float)(0.5 * ((double)S1x - (double)S2x))); \
    } else { \
      int k2 = 512 - k; \
      float m1 = mrow[k];  float2 a1 = A[SL(k)]; \
      float m2 = mrow[k2]; float2 a2 = A[SL(k2)]; \
      float S1x = __fmul_rn(m1, a1.x), S1y = __fmul_rn(m1, a1.y); \
      float S2x = __fmul_rn(m2, a2.x), S2y = __fmul_rn(m2, a2.y); \
      double Xex = 0.5 * ((double)S1x + (double)S2x); \
      double Xey = 0.5 * ((double)S1y - (double)S2y); \
      double Dx  = 0.5 * ((double)S1x - (double)S2x); \
      double Dy  = 0.5 * ((double)S1y + (double)S2y); \
      double2 w = twh[k]; \
      double ux = w.x * Dx + w.y * Dy; \
      double uy = w.x * Dy - w.y * Dx; \
      zj = make_float2((float)(Xex - uy), (float)(Xey + ux)); \
    } }
  PACKL(0, z0) PACKL(1, z1) PACKL(2, z2) PACKL(3, z3)
  PACKL(4, z4) PACKL(5, z5) PACKL(6, z6) PACKL(7, z7)
  WAVEFENCE();   // all PACKL reads issued before stage0 overwrites A (cross-lane)

  stage0_regs<true>(A, twl, t, z0, z1, z2, z3, z4, z5, z6, z7);
  WAVEFENCE();
  stage_mid<true>(A, twl, t);
  WAVEFENCE();
  float2 y0, y1, y2, y3, y4, y5, y6, y7;
  stage_last_regs<true>(A, t, y0, y1, y2, y3, y4, y5, y6, y7);

  const float sc = 1.0f / 512.0f;
  float2* frow2 = (float2*)(frames + bf * NFFT);
  STOREF(0, y0) STOREF(1, y1) STOREF(2, y2) STOREF(3, y3)
  STOREF(4, y4) STOREF(5, y5) STOREF(6, y6) STOREF(7, y7)
}

// ---------------- final OLA -> audio f32 + per-block |max| ----------------
__global__ __launch_bounds__(256) void k_ola(const float* __restrict__ frames, const float* __restrict__ wsq,
                                             float* __restrict__ audio, float* __restrict__ partial)
{
  int idx = blockIdx.x * 256 + threadIdx.x;
  int b  = idx >> 17;
  int nn = idx & (NSAMP - 1);
  float v = 0.f;
  if (nn < SIGLEN)
    v = sig_sample(frames + b * (NW * NFFT), wsq, nn + 512);
  audio[idx] = v;
  __shared__ float red[256];
  red[threadIdx.x] = fabsf(v);
  __syncthreads();
  for (int s = 128; s > 0; s >>= 1) {
    if (threadIdx.x < s) red[threadIdx.x] = fmaxf(red[threadIdx.x], red[threadIdx.x + s]);
    __syncthreads();
  }
  if (threadIdx.x == 0) partial[blockIdx.x] = red[0];
}

constexpr int OLA_BLK_PER_B = NSAMP / 256;   // 512

__global__ __launch_bounds__(256) void k_max2(const float* __restrict__ partial, float* __restrict__ maxbuf)
{
  int b = blockIdx.x;
  float m = 0.f;
  for (int i = threadIdx.x; i < OLA_BLK_PER_B; i += 256)
    m = fmaxf(m, partial[b * OLA_BLK_PER_B + i]);
  __shared__ float red[256];
  red[threadIdx.x] = m;
  __syncthreads();
  for (int s = 128; s > 0; s >>= 1) {
    if (threadIdx.x < s) red[threadIdx.x] = fmaxf(red[threadIdx.x], red[threadIdx.x + s]);
    __syncthreads();
  }
  if (threadIdx.x == 0) maxbuf[b] = red[0];
}

__global__ __launch_bounds__(256) void k_norm(const float* __restrict__ audio, const float* __restrict__ maxbuf,
                                              float* __restrict__ out)
{
  int idx = blockIdx.x * 256 + threadIdx.x;
  int b = idx >> 17;
  float m = fmaxf(maxbuf[b], 1e-8f);
  out[idx] = __fmul_rn(__fdiv_rn(audio[idx], m), 0.9f);
}

extern "C" void kernel_launch(void* const* d_in, const int* in_sizes, int n_in,
                              void* d_out, int out_size, void* d_ws, size_t ws_size,
                              hipStream_t stream)
{
  const float* params = (const float*)d_in[0];
  float* out   = (float*)d_out;
  float* audio_out = out;                   // BATCH*NSAMP
  float* fs        = out + BATCH * NSAMP;   // BATCH*FH*FW (full_spec output)

  float2*  tw512f = (float2*)d_ws;                         // 512
  double2* twh    = (double2*)(tw512f + 512);              // 512
  float2*  ang    = (float2*)(twh + 512);                  // NMAG c64 (initial phases only)
  float2*  tprev  = ang + NMAG;                            // NMAG c64
  float*   frames = (float*)(tprev + NMAG);                // BATCH*NW*NFFT f32
  float*   mag    = frames + BATCH * NW * NFFT;            // NMAG f32
  float*   xp     = mag + NMAG;                            // BATCH*TOTAL_LEN f32
  float*   win    = xp + BATCH * TOTAL_LEN;                // NFFT
  float*   wsq    = win + NFFT;                            // TOTAL_LEN
  float*   audio32= wsq + TOTAL_LEN;                       // BATCH*NSAMP
  float*   maxbuf = audio32 + BATCH * NSAMP;               // BATCH
  float*   partial= maxbuf + BATCH;                        // BATCH*OLA_BLK_PER_B

  k_init<<<512, 256, 0, stream>>>(win, tw512f, twh, wsq, tprev);
  k_fullspec<<<(BATCH * FH * FW) / 256, 256, 0, stream>>>(params, fs);
  k_mag<<<(NMAG + 255) / 256, 256, 0, stream>>>(params, mag);
  k_phase<<<(NMAG + 255) / 256, 256, 0, stream>>>(ang);

  k_istft<<<BATCH * NW / 4, 256, 0, stream>>>(mag, (const float2*)ang, frames, tw512f, twh, win);
  for (int it = 0; it < NITER; ++it) {
    k_sig<<<(BATCH * TOTAL_LEN) / 256, 256, 0, stream>>>(frames, wsq, xp);
    k_fused<<<BATCH * NW / 4, 256, 0, stream>>>(xp, win, tw512f, twh, mag, tprev, frames);
  }
  k_ola<<<(BATCH * NSAMP) / 256, 256, 0, stream>>>(frames, wsq, audio32, partial);
  k_max2<<<BATCH, 256, 0, stream>>>(partial, maxbuf);
  k_norm<<<(BATCH * NSAMP) / 256, 256, 0, stream>>>(audio32, maxbuf, audio_out);
}